// Round 7
// baseline (776.136 us; speedup 1.0000x reference)
//
#include <hip/hip_runtime.h>
#include <hip/hip_bf16.h>

using bf16 = __hip_bfloat16;
typedef __attribute__((ext_vector_type(8))) __bf16 bf16x8;
typedef __attribute__((ext_vector_type(4))) float f32x4;

static __device__ __forceinline__ bf16 f2b(float v) { return __float2bfloat16(v); }
static __device__ __forceinline__ float us2f(unsigned short u) {
    return __uint_as_float(((unsigned)u) << 16);
}

// Problem: B=2, C=64, H=48, W=64, D=49, BD=98. fp32 I/O.
// Fully-MFMA pipeline, NHWC bf16, barrier-free direct-from-global fragments.

// ---------------------------------------------------------------------------
__global__ void sentinel_k(float* __restrict__ out, int nel, float val) {
    int i = blockIdx.x * 256 + threadIdx.x;
    if (i < nel) out[i] = val;
}

// ---------------------------------------------------------------------------
// Weight packing: wp[t][oc][ic] bf16
// ---------------------------------------------------------------------------
__global__ void pack_w0(const float* __restrict__ w0, bf16* __restrict__ wp, int icbase) {
    int i = blockIdx.x * 256 + threadIdx.x;
    if (i >= 9 * 96 * 64) return;
    int ic = i % 64, oc = (i / 64) % 96, t = i / (64 * 96);
    wp[i] = f2b(w0[((size_t)oc * 128 + icbase + ic) * 9 + t]);
}

__global__ void pack_simple(const float* __restrict__ w, bf16* __restrict__ wp,
                            int OC, int IC, int T) {
    int i = blockIdx.x * 256 + threadIdx.x;
    if (i >= T * OC * IC) return;
    int ic = i % IC, oc = (i / IC) % OC, t = i / (IC * OC);
    wp[i] = f2b(w[((size_t)oc * IC + ic) * T + t]);
}

// conv1 parity-plane weights: wp1[t2][128][384], t2=(dy+1)*2+(dx+1), dy,dx in {-1,0}
__global__ void pack_w1(const float* __restrict__ w1, bf16* __restrict__ wp) {
    int i = blockIdx.x * 256 + threadIdx.x;
    if (i >= 4 * 128 * 384) return;
    int pc = i % 384, oc = (i / 384) % 128, t2 = i / (384 * 128);
    int dy = (t2 < 2) ? -1 : 0;
    int dx = (t2 & 1) ? 0 : -1;
    int p = pc / 96, ic = pc % 96;
    int py = p >> 1, px = p & 1;
    int ky = (dy == -1) ? (py == 1 ? 0 : -1) : (py == 0 ? 1 : 2);
    int kx = (dx == -1) ? (px == 1 ? 0 : -1) : (px == 0 ? 1 : 2);
    float v = (ky >= 0 && kx >= 0) ? w1[((size_t)oc * 96 + ic) * 9 + ky * 3 + kx] : 0.f;
    wp[i] = f2b(v);
}

// deconv class weights: wpd[c][t2][32][64], c=qy*2+qx, dy=qy-1+t2/2, dx=qx-1+t2%2
__global__ void pack_wd(const float* __restrict__ wd, bf16* __restrict__ wp) {
    int i = blockIdx.x * 256 + threadIdx.x;
    if (i >= 4 * 4 * 32 * 64) return;
    int ic = i % 64, oc = (i / 64) % 32, t2 = (i / 2048) % 4, c = i / 8192;
    int qy = c >> 1, qx = c & 1;
    int dy = qy - 1 + (t2 >> 1), dx = qx - 1 + (t2 & 1);
    int ky = (qy == 0) ? (dy == -1 ? 0 : 2) : (dy == 0 ? 1 : 3);
    int kx = (qx == 0) ? (dx == -1 ? 0 : 2) : (dx == 0 ? 1 : 3);
    wp[i] = f2b(wd[((size_t)oc * 64 + ic) * 16 + ky * 4 + kx]);
}

// ---------------------------------------------------------------------------
// NCHW fp32 (2,64,48,64) -> NHWC bf16 (2,48,64,64)
// ---------------------------------------------------------------------------
__global__ void to_nhwc(const float* __restrict__ src, bf16* __restrict__ dst) {
    int i = blockIdx.x * 256 + threadIdx.x;
    if (i >= 2 * 3072 * 64) return;
    int c = i & 63;
    int p = (i >> 6) % 3072;
    int b = i / (3072 * 64);
    dst[i] = f2b(src[((size_t)b * 64 + c) * 3072 + p]);
}

// ---------------------------------------------------------------------------
// warp: bilinear from f2n (NHWC bf16). thread = (pixel, 4-channel group).
// ---------------------------------------------------------------------------
__global__ __launch_bounds__(256) void warp_kernel(const bf16* __restrict__ f2n,
                                                   const float* __restrict__ coords,
                                                   bf16* __restrict__ f2w, int bd0, int cnt) {
    int idx = blockIdx.x * 256 + threadIdx.x;
    if (idx >= cnt * 3072 * 16) return;
    int g = idx & 15;
    int pix = idx >> 4;
    int p = pix % 3072;
    int z = pix / 3072;
    int bd = bd0 + z;
    int b = bd / 49, d = bd % 49;
    float du = (float)(d % 7 - 3), dv = (float)(d / 7 - 3);
    float cx = coords[(size_t)(b * 2 + 0) * 3072 + p] + du;
    float cy = coords[(size_t)(b * 2 + 1) * 3072 + p] + dv;
    float x0f = floorf(cx), y0f = floorf(cy);
    float wx = cx - x0f, wy = cy - y0f;
    int x0 = (int)x0f, y0 = (int)y0f;
    int x1 = x0 + 1, y1 = y0 + 1;
    bool vx0 = (x0 >= 0) && (x0 < 64), vx1 = (x1 >= 0) && (x1 < 64);
    bool vy0 = (y0 >= 0) && (y0 < 48), vy1 = (y1 >= 0) && (y1 < 48);
    int xc0 = min(max(x0, 0), 63), xc1 = min(max(x1, 0), 63);
    int yc0 = min(max(y0, 0), 47), yc1 = min(max(y1, 0), 47);
    float w00 = (vx0 && vy0) ? (1.f - wx) * (1.f - wy) : 0.f;
    float w01 = (vx1 && vy0) ? wx * (1.f - wy) : 0.f;
    float w10 = (vx0 && vy1) ? (1.f - wx) * wy : 0.f;
    float w11 = (vx1 && vy1) ? wx * wy : 0.f;
    const unsigned short* f2 = (const unsigned short*)f2n + (size_t)b * 3072 * 64 + g * 4;
    ushort4 u00 = *(const ushort4*)(f2 + (size_t)(yc0 * 64 + xc0) * 64);
    ushort4 u01 = *(const ushort4*)(f2 + (size_t)(yc0 * 64 + xc1) * 64);
    ushort4 u10 = *(const ushort4*)(f2 + (size_t)(yc1 * 64 + xc0) * 64);
    ushort4 u11 = *(const ushort4*)(f2 + (size_t)(yc1 * 64 + xc1) * 64);
    float v0 = w00 * us2f(u00.x) + w01 * us2f(u01.x) + w10 * us2f(u10.x) + w11 * us2f(u11.x);
    float v1 = w00 * us2f(u00.y) + w01 * us2f(u01.y) + w10 * us2f(u10.y) + w11 * us2f(u11.y);
    float v2 = w00 * us2f(u00.z) + w01 * us2f(u01.z) + w10 * us2f(u10.z) + w11 * us2f(u11.z);
    float v3 = w00 * us2f(u00.w) + w01 * us2f(u01.w) + w10 * us2f(u10.w) + w11 * us2f(u11.w);
    bf16 r0 = f2b(v0), r1 = f2b(v1), r2 = f2b(v2), r3 = f2b(v3);
    ushort4 o = {*(unsigned short*)&r0, *(unsigned short*)&r1,
                 *(unsigned short*)&r2, *(unsigned short*)&r3};
    *(ushort4*)((unsigned short*)f2w + ((size_t)z * 3072 + p) * 64 + g * 4) = o;
}

// ---------------------------------------------------------------------------
// Barrier-free MFMA implicit-GEMM conv, fragments direct from global.
// 256 threads = 4 waves: wy = px-half (64 px, 4 frags), wx = oc-half of OC_BLK.
// Tile: 128 px (MROWS*W) x OC_BLK. grid = (H/MROWS, ocg-or-class, z).
// A frag: lane m = pixel (x-contiguous, W%16==0), 16B load, per-lane bounds->0.
// B frag: lane m = oc, from wp[t][oc][ic], 16B load.
// BMODE: 0 bias fp32[OCTOT]; 1 base NHWC fp32 (2,48,64,96), b=(bd0+z)/49.
// OMODE: 0 plain NHWC bf16+ReLU; 1 parity-pack into (cnt,24,32,384);
//        2 stride-2 scatter into (cnt,48,64,32) at (2y+qy,2x+qx); 3 fp32, no ReLU.
// CLS=1 (deconv): blockIdx.y = class c; wp += c*NTAPS*OCTOT*IC; taps from qy,qx.
// ---------------------------------------------------------------------------
template <int IC, int OCTOT, int OC_BLK, int H, int W, int MROWS, int NTAPS, int DXW,
          int DYLO, int DXLO, int BMODE, int OMODE, int CLS>
__global__ __launch_bounds__(256, 4) void conv_direct(const bf16* __restrict__ in_,
                                                      const bf16* __restrict__ wp_,
                                                      const float* __restrict__ bias,
                                                      const float* __restrict__ base,
                                                      bf16* __restrict__ out, int bd0) {
    constexpr int NCH = IC / 32;
    constexpr int NfT = OC_BLK / 32;
    const unsigned short* in = (const unsigned short*)in_;
    const unsigned short* wp = (const unsigned short*)wp_;
    const int tid = threadIdx.x;
    const int wave = tid >> 6, lane = tid & 63;
    const int m = lane & 15, q = lane >> 4;
    const int wy = wave >> 1, wx = wave & 1;
    const int bx = blockIdx.x, by = blockIdx.y, z = blockIdx.z;

    int ocbase, dylo, dxlo, oqy = 0, oqx = 0;
    if constexpr (CLS == 1) {
        oqy = by >> 1; oqx = by & 1;
        dylo = oqy - 1; dxlo = oqx - 1;
        wp += (size_t)by * NTAPS * OCTOT * IC;
        ocbase = 0;
    } else {
        ocbase = by * OC_BLK;
        dylo = DYLO; dxlo = DXLO;
    }

    f32x4 acc[4][NfT];
#pragma unroll
    for (int a = 0; a < 4; ++a)
#pragma unroll
        for (int nf = 0; nf < NfT; ++nf) acc[a][nf] = (f32x4){0.f, 0.f, 0.f, 0.f};

    for (int cc = 0; cc < NCH; ++cc) {
#pragma unroll
        for (int t = 0; t < NTAPS; ++t) {
            const int dy = dylo + t / DXW;
            const int dx = dxlo + t % DXW;
            bf16x8 af[4];
#pragma unroll
            for (int mf = 0; mf < 4; ++mf) {
                const int pxb = wy * 64 + mf * 16;
                const int yl = pxb / W, xb = pxb % W;
                const int gy = bx * MROWS + yl + dy;
                const int gx = xb + m + dx;
                uint4 u = {0u, 0u, 0u, 0u};
                if (gy >= 0 && gy < H && gx >= 0 && gx < W)
                    u = *(const uint4*)(in + ((size_t)(z * H + gy) * W + gx) * IC + cc * 32 + q * 8);
                af[mf] = __builtin_bit_cast(bf16x8, u);
            }
            bf16x8 bfr[NfT];
#pragma unroll
            for (int nf = 0; nf < NfT; ++nf) {
                const int oc = ocbase + wx * (OC_BLK / 2) + nf * 16 + m;
                bfr[nf] = *(const bf16x8*)(wp + ((size_t)t * OCTOT + oc) * IC + cc * 32 + q * 8);
            }
#pragma unroll
            for (int mf = 0; mf < 4; ++mf)
#pragma unroll
                for (int nf = 0; nf < NfT; ++nf)
                    acc[mf][nf] =
                        __builtin_amdgcn_mfma_f32_16x16x32_bf16(af[mf], bfr[nf], acc[mf][nf], 0, 0, 0);
        }
    }

    const int b = (bd0 + z) / 49;
#pragma unroll
    for (int mf = 0; mf < 4; ++mf) {
        const int pxb = wy * 64 + mf * 16;
#pragma unroll
        for (int r = 0; r < 4; ++r) {
            const int px = pxb + q * 4 + r;
            const int yl = px / W, xl = px % W;
            const int gy = bx * MROWS + yl;
#pragma unroll
            for (int nf = 0; nf < NfT; ++nf) {
                const int oc = ocbase + wx * (OC_BLK / 2) + nf * 16 + m;
                float v = acc[mf][nf][r];
                if constexpr (BMODE == 1)
                    v += base[(((size_t)b * 48 + gy) * 64 + xl) * 96 + oc];
                else
                    v += bias[oc];
                if constexpr (OMODE == 3) {
                    ((float*)out)[(((size_t)z * H + gy) * W + xl) * OCTOT + oc] = v;
                } else {
                    v = fmaxf(v, 0.f);
                    bf16 bv = f2b(v);
                    if constexpr (OMODE == 0) {
                        out[(((size_t)z * H + gy) * W + xl) * OCTOT + oc] = bv;
                    } else if constexpr (OMODE == 1) {
                        int yy = gy >> 1, xx = xl >> 1, pp = (gy & 1) * 2 + (xl & 1);
                        out[(((size_t)z * 24 + yy) * 32 + xx) * 384 + pp * 96 + oc] = bv;
                    } else {
                        out[(((size_t)z * 48 + 2 * gy + oqy) * 64 + 2 * xl + oqx) * 32 + oc] = bv;
                    }
                }
            }
        }
    }
}

// ---------------------------------------------------------------------------
// conv5: 3x3, 32->1, no ReLU. in NHWC bf16 (cnt,48,64,32) -> cost fp32
// ---------------------------------------------------------------------------
__global__ __launch_bounds__(256) void conv5_k(const bf16* __restrict__ in_,
                                               const float* __restrict__ w5,
                                               const float* __restrict__ b5,
                                               float* __restrict__ cost, int bd0, int cnt) {
    __shared__ float s_w5[9][32];
    const int tid = threadIdx.x;
    for (int i = tid; i < 288; i += 256) {
        int ic = i % 32, t = i / 32;
        s_w5[t][ic] = w5[ic * 9 + t];
    }
    __syncthreads();
    int idx = blockIdx.x * 256 + tid;
    if (idx >= cnt * 3072) return;
    int p = idx % 3072, z = idx / 3072;
    int y = p >> 6, x = p & 63;
    const unsigned short* in = (const unsigned short*)in_;
    float acc = b5[0];
#pragma unroll
    for (int ky = 0; ky < 3; ++ky) {
        int gy = y + ky - 1;
        if (gy < 0 || gy >= 48) continue;
#pragma unroll
        for (int kx = 0; kx < 3; ++kx) {
            int gx = x + kx - 1;
            if (gx < 0 || gx >= 64) continue;
            const ushort4* src = (const ushort4*)(in + ((size_t)(z * 48 + gy) * 64 + gx) * 32);
            const float* wr = s_w5[ky * 3 + kx];
#pragma unroll
            for (int e = 0; e < 8; ++e) {
                ushort4 u = src[e];
                acc = fmaf(us2f(u.x), wr[e * 4 + 0], acc);
                acc = fmaf(us2f(u.y), wr[e * 4 + 1], acc);
                acc = fmaf(us2f(u.z), wr[e * 4 + 2], acc);
                acc = fmaf(us2f(u.w), wr[e * 4 + 3], acc);
            }
        }
    }
    cost[(size_t)(bd0 + z) * 3072 + p] = acc;
}

// ---------------------------------------------------------------------------
// DAP (49x49) + softmax + flow expectation + coords. out fp32 (2,2,48,64)
// ---------------------------------------------------------------------------
__global__ __launch_bounds__(256) void dap_flow(const float* __restrict__ cost,
                                                const float* __restrict__ wdap,
                                                const float* __restrict__ coords,
                                                float* __restrict__ outp) {
    __shared__ float s_w[49 * 49];
    int tid = threadIdx.x;
    for (int i = tid; i < 2401; i += 256) s_w[i] = wdap[i];
    __syncthreads();
    int idx = blockIdx.x * 256 + tid;
    if (idx >= 2 * 3072) return;
    int p = idx % 3072, b = idx / 3072;
    float c[49];
#pragma unroll
    for (int d = 0; d < 49; ++d) c[d] = cost[((size_t)(b * 49 + d)) * 3072 + p];
    float mx = -1e30f;
    for (int e = 0; e < 49; ++e) {
        float s = 0.f;
#pragma unroll
        for (int d = 0; d < 49; ++d) s = fmaf(s_w[e * 49 + d], c[d], s);
        mx = fmaxf(mx, s);
    }
    float sum = 0.f, sx = 0.f, sy = 0.f;
    for (int e = 0; e < 49; ++e) {
        float s = 0.f;
#pragma unroll
        for (int d = 0; d < 49; ++d) s = fmaf(s_w[e * 49 + d], c[d], s);
        float pr = __expf(s - mx);
        sum += pr;
        sx += pr * (float)(e % 7 - 3);
        sy += pr * (float)(e / 7 - 3);
    }
    float inv = 1.f / sum;
    outp[(size_t)(b * 2 + 0) * 3072 + p] = coords[(size_t)(b * 2 + 0) * 3072 + p] + sx * inv;
    outp[(size_t)(b * 2 + 1) * 3072 + p] = coords[(size_t)(b * 2 + 1) * 3072 + p] + sy * inv;
}

// ---------------------------------------------------------------------------
extern "C" void kernel_launch(void* const* d_in, const int* in_sizes, int n_in,
                              void* d_out, int out_size, void* d_ws, size_t ws_size,
                              hipStream_t stream) {
    (void)in_sizes; (void)n_in;
    const float* feat1 = (const float*)d_in[0];
    const float* feat2 = (const float*)d_in[1];
    const float* coords = (const float*)d_in[2];
    const float* w0 = (const float*)d_in[3];
    const float* b0 = (const float*)d_in[4];
    const float* w1 = (const float*)d_in[5];
    const float* b1 = (const float*)d_in[6];
    const float* w2 = (const float*)d_in[7];
    const float* b2 = (const float*)d_in[8];
    const float* w3 = (const float*)d_in[9];
    const float* b3 = (const float*)d_in[10];
    const float* wd = (const float*)d_in[11];
    const float* bdc = (const float*)d_in[12];
    const float* w5 = (const float*)d_in[13];
    const float* b5 = (const float*)d_in[14];
    const float* wdap = (const float*)d_in[15];
    float* outp = (float*)d_out;

    // workspace layout (fixed):
    //  wp0 @0 (110592) | wp0a @110592 (110592) | wp1 @221184 (393216)
    //  wp2 @614400 (294912) | wp3 @909312 (147456) | wpd @1056768 (65536)
    //  f1n @1122304 (786432) | part0 @1908736 (2359296) | cost @4268032 (1204224)
    //  f2n @5472256 (786432) | fixed_end = 6258688
    char* ws = (char*)d_ws;
    bf16* wp0 = (bf16*)(ws + 0);
    bf16* wp0a = (bf16*)(ws + 110592);
    bf16* wp1 = (bf16*)(ws + 221184);
    bf16* wp2 = (bf16*)(ws + 614400);
    bf16* wp3 = (bf16*)(ws + 909312);
    bf16* wpd = (bf16*)(ws + 1056768);
    bf16* f1n = (bf16*)(ws + 1122304);
    float* part0 = (float*)(ws + 1908736);
    float* cost = (float*)(ws + 4268032);
    bf16* f2n = (bf16*)(ws + 5472256);
    const size_t fixed_end = 6258688;

    const int cand[7] = {98, 49, 25, 14, 7, 2, 1};
    int nb = 0;
    for (int i = 0; i < 7; ++i) {
        if (fixed_end + (size_t)983040 * cand[i] <= ws_size) { nb = cand[i]; break; }
    }
    if (nb == 0) {
        float val = 10000.f + (float)(ws_size >> 20);
        sentinel_k<<<dim3((out_size + 255) / 256), 256, 0, stream>>>(outp, out_size, val);
        return;
    }
    char* regA = ws + fixed_end;
    char* regB = regA + (size_t)393216 * nb;
    bf16* f2w = (bf16*)regA;  // (nb,48,64,64)
    bf16* x1 = (bf16*)regA;   // (nb,24,32,128)
    bf16* x3 = (bf16*)regA;   // (nb,24,32,64)
    bf16* x0p = (bf16*)regB;  // (nb,24,32,384) parity-packed
    bf16* x2 = (bf16*)regB;   // (nb,24,32,128)
    bf16* xd = (bf16*)regB;   // (nb,48,64,32)

    // packing + transposes + part0 (once per call)
    pack_w0<<<dim3(216), 256, 0, stream>>>(w0, wp0, 64);
    pack_w0<<<dim3(216), 256, 0, stream>>>(w0, wp0a, 0);
    pack_w1<<<dim3(768), 256, 0, stream>>>(w1, wp1);
    pack_simple<<<dim3(576), 256, 0, stream>>>(w2, wp2, 128, 128, 9);
    pack_simple<<<dim3(288), 256, 0, stream>>>(w3, wp3, 64, 128, 9);
    pack_wd<<<dim3(128), 256, 0, stream>>>(wd, wpd);
    to_nhwc<<<dim3(1536), 256, 0, stream>>>(feat1, f1n);
    to_nhwc<<<dim3(1536), 256, 0, stream>>>(feat2, f2n);
    // part0 = conv3x3(f1n, w0[:,:64]) + b0 -> fp32 NHWC, no ReLU
    conv_direct<64, 96, 96, 48, 64, 2, 9, 3, -1, -1, 0, 3, 0>
        <<<dim3(24, 1, 2), 256, 0, stream>>>(f1n, wp0a, b0, nullptr, (bf16*)part0, 0);

    for (int s = 0; s < 98; s += nb) {
        int cnt = (98 - s < nb) ? (98 - s) : nb;
        warp_kernel<<<dim3(cnt * 192), 256, 0, stream>>>(f2n, coords, f2w, s, cnt);
        // conv0: IC=64 taps3x3 OC=96, base=part0, out parity-packed
        conv_direct<64, 96, 96, 48, 64, 2, 9, 3, -1, -1, 1, 1, 0>
            <<<dim3(24, 1, cnt), 256, 0, stream>>>(f2w, wp0, nullptr, part0, x0p, s);
        // conv1: IC=384 taps{-1,0}^2 OC=128, oc split 2
        conv_direct<384, 128, 64, 24, 32, 4, 4, 2, -1, -1, 0, 0, 0>
            <<<dim3(6, 2, cnt), 256, 0, stream>>>(x0p, wp1, b1, nullptr, x1, s);
        // conv2: IC=128 taps3x3 OC=128, oc split 2
        conv_direct<128, 128, 64, 24, 32, 4, 9, 3, -1, -1, 0, 0, 0>
            <<<dim3(6, 2, cnt), 256, 0, stream>>>(x1, wp2, b2, nullptr, x2, s);
        // conv3: IC=128 taps3x3 OC=64, oc split 2
        conv_direct<128, 64, 32, 24, 32, 4, 9, 3, -1, -1, 0, 0, 0>
            <<<dim3(6, 2, cnt), 256, 0, stream>>>(x2, wp3, b3, nullptr, x3, s);
        // deconv: 4 parity classes in one launch (blockIdx.y = class)
        conv_direct<64, 32, 32, 24, 32, 4, 4, 2, 0, 0, 0, 2, 1>
            <<<dim3(6, 4, cnt), 256, 0, stream>>>(x3, wpd, bdc, nullptr, xd, s);
        // conv5
        conv5_k<<<dim3(cnt * 12), 256, 0, stream>>>(xd, w5, b5, cost, s, cnt);
    }

    dap_flow<<<dim3(24), 256, 0, stream>>>(cost, wdap, coords, outp);
}

// Round 8
// 433.103 us; speedup vs baseline: 1.7920x; 1.7920x over previous
//
#include <hip/hip_runtime.h>
#include <hip/hip_bf16.h>

using bf16 = __hip_bfloat16;
typedef __attribute__((ext_vector_type(8))) __bf16 bf16x8;
typedef __attribute__((ext_vector_type(4))) float f32x4;

static __device__ __forceinline__ bf16 f2b(float v) { return __float2bfloat16(v); }
static __device__ __forceinline__ float us2f(unsigned short u) {
    return __uint_as_float(((unsigned)u) << 16);
}

// Problem: B=2, C=64, H=48, W=64, D=49, BD=98. fp32 I/O.
// MFMA pipeline, NHWC bf16. A staged in LDS (coalesced, 2 barriers per ic-chunk);
// B pre-swizzled to MFMA fragment order -> one coalesced 16B/lane global load per
// frag, no LDS, no barriers for B.

// ---------------------------------------------------------------------------
__global__ void sentinel_k(float* __restrict__ out, int nel, float val) {
    int i = blockIdx.x * 256 + threadIdx.x;
    if (i < nel) out[i] = val;
}

// ---------------------------------------------------------------------------
// Fragment-order weight packing.
// Layout: o = (((t*NOCF + ocf)*NCH + cc)*64 + lane)*8 + j
//   lane = q*16+m;  element j holds W[k=cc*32+q*8+j][oc=ocf*16+m] for tap t.
// ---------------------------------------------------------------------------
__global__ void pack_w0_sw(const float* __restrict__ w0, bf16* __restrict__ out, int icbase) {
    int o = blockIdx.x * 256 + threadIdx.x;
    if (o >= 9 * 6 * 2 * 512) return;  // T=9, NOCF=6, NCH=2
    int j = o & 7, lane = (o >> 3) & 63;
    int m = lane & 15, q = lane >> 4;
    int cc = (o >> 9) & 1;
    int fragid = o >> 10;
    int t = fragid / 6, ocf = fragid % 6;
    int oc = ocf * 16 + m, ic = cc * 32 + q * 8 + j;
    out[o] = f2b(w0[((size_t)oc * 128 + icbase + ic) * 9 + t]);
}

// generic [t][oc][ic] source with src w[(oc*IC+ic)*T + t]
template <int OC, int IC, int T>
__global__ void pack_sw(const float* __restrict__ w, bf16* __restrict__ out) {
    constexpr int NOCF = OC / 16, NCH = IC / 32;
    int o = blockIdx.x * 256 + threadIdx.x;
    if (o >= T * NOCF * NCH * 512) return;
    int j = o & 7, lane = (o >> 3) & 63;
    int m = lane & 15, q = lane >> 4;
    int cc = (o >> 9) % NCH;
    int fragid = (o >> 9) / NCH;
    int t = fragid / NOCF, ocf = fragid % NOCF;
    int oc = ocf * 16 + m, ic = cc * 32 + q * 8 + j;
    out[o] = f2b(w[((size_t)oc * IC + ic) * T + t]);
}

// conv1 parity-plane weights, frag order. T=4 (t2), OC=128, IC=384.
__global__ void pack_w1_sw(const float* __restrict__ w1, bf16* __restrict__ out) {
    int o = blockIdx.x * 256 + threadIdx.x;
    if (o >= 4 * 8 * 12 * 512) return;  // NOCF=8, NCH=12
    int j = o & 7, lane = (o >> 3) & 63;
    int m = lane & 15, q = lane >> 4;
    int cc = (o >> 9) % 12;
    int fragid = (o >> 9) / 12;
    int t2 = fragid / 8, ocf = fragid % 8;
    int oc = ocf * 16 + m;
    int pc = cc * 32 + q * 8 + j;
    int dy = (t2 < 2) ? -1 : 0;
    int dx = (t2 & 1) ? 0 : -1;
    int p = pc / 96, ic = pc % 96;
    int py = p >> 1, px = p & 1;
    int ky = (dy == -1) ? (py == 1 ? 0 : -1) : (py == 0 ? 1 : 2);
    int kx = (dx == -1) ? (px == 1 ? 0 : -1) : (px == 0 ? 1 : 2);
    float v = (ky >= 0 && kx >= 0) ? w1[((size_t)oc * 96 + ic) * 9 + ky * 3 + kx] : 0.f;
    out[o] = f2b(v);
}

// deconv class weights, frag order. 4 classes x (T=4, NOCF=2, NCH=2).
__global__ void pack_wd_sw(const float* __restrict__ wd, bf16* __restrict__ out) {
    int o = blockIdx.x * 256 + threadIdx.x;
    if (o >= 4 * 4 * 2 * 2 * 512) return;
    int j = o & 7, lane = (o >> 3) & 63;
    int m = lane & 15, q = lane >> 4;
    int cc = (o >> 9) & 1;
    int ocf = (o >> 10) & 1;
    int t2 = (o >> 11) & 3;
    int c = o >> 13;
    int oc = ocf * 16 + m, ic = cc * 32 + q * 8 + j;
    int qy = c >> 1, qx = c & 1;
    int dy = qy - 1 + (t2 >> 1), dx = qx - 1 + (t2 & 1);
    int ky = (qy == 0) ? (dy == -1 ? 0 : 2) : (dy == 0 ? 1 : 3);
    int kx = (qx == 0) ? (dx == -1 ? 0 : 2) : (dx == 0 ? 1 : 3);
    out[o] = f2b(wd[((size_t)oc * 64 + ic) * 16 + ky * 4 + kx]);
}

// ---------------------------------------------------------------------------
// NCHW fp32 (2,64,48,64) -> NHWC bf16 (2,48,64,64)
// ---------------------------------------------------------------------------
__global__ void to_nhwc(const float* __restrict__ src, bf16* __restrict__ dst) {
    int i = blockIdx.x * 256 + threadIdx.x;
    if (i >= 2 * 3072 * 64) return;
    int c = i & 63;
    int p = (i >> 6) % 3072;
    int b = i / (3072 * 64);
    dst[i] = f2b(src[((size_t)b * 64 + c) * 3072 + p]);
}

// ---------------------------------------------------------------------------
// warp: bilinear from f2n (NHWC bf16). thread = (pixel, 4-channel group).
// ---------------------------------------------------------------------------
__global__ __launch_bounds__(256) void warp_kernel(const bf16* __restrict__ f2n,
                                                   const float* __restrict__ coords,
                                                   bf16* __restrict__ f2w, int bd0, int cnt) {
    int idx = blockIdx.x * 256 + threadIdx.x;
    if (idx >= cnt * 3072 * 16) return;
    int g = idx & 15;
    int pix = idx >> 4;
    int p = pix % 3072;
    int z = pix / 3072;
    int bd = bd0 + z;
    int b = bd / 49, d = bd % 49;
    float du = (float)(d % 7 - 3), dv = (float)(d / 7 - 3);
    float cx = coords[(size_t)(b * 2 + 0) * 3072 + p] + du;
    float cy = coords[(size_t)(b * 2 + 1) * 3072 + p] + dv;
    float x0f = floorf(cx), y0f = floorf(cy);
    float wx = cx - x0f, wy = cy - y0f;
    int x0 = (int)x0f, y0 = (int)y0f;
    int x1 = x0 + 1, y1 = y0 + 1;
    bool vx0 = (x0 >= 0) && (x0 < 64), vx1 = (x1 >= 0) && (x1 < 64);
    bool vy0 = (y0 >= 0) && (y0 < 48), vy1 = (y1 >= 0) && (y1 < 48);
    int xc0 = min(max(x0, 0), 63), xc1 = min(max(x1, 0), 63);
    int yc0 = min(max(y0, 0), 47), yc1 = min(max(y1, 0), 47);
    float w00 = (vx0 && vy0) ? (1.f - wx) * (1.f - wy) : 0.f;
    float w01 = (vx1 && vy0) ? wx * (1.f - wy) : 0.f;
    float w10 = (vx0 && vy1) ? (1.f - wx) * wy : 0.f;
    float w11 = (vx1 && vy1) ? wx * wy : 0.f;
    const unsigned short* f2 = (const unsigned short*)f2n + (size_t)b * 3072 * 64 + g * 4;
    ushort4 u00 = *(const ushort4*)(f2 + (size_t)(yc0 * 64 + xc0) * 64);
    ushort4 u01 = *(const ushort4*)(f2 + (size_t)(yc0 * 64 + xc1) * 64);
    ushort4 u10 = *(const ushort4*)(f2 + (size_t)(yc1 * 64 + xc0) * 64);
    ushort4 u11 = *(const ushort4*)(f2 + (size_t)(yc1 * 64 + xc1) * 64);
    float v0 = w00 * us2f(u00.x) + w01 * us2f(u01.x) + w10 * us2f(u10.x) + w11 * us2f(u11.x);
    float v1 = w00 * us2f(u00.y) + w01 * us2f(u01.y) + w10 * us2f(u10.y) + w11 * us2f(u11.y);
    float v2 = w00 * us2f(u00.z) + w01 * us2f(u01.z) + w10 * us2f(u10.z) + w11 * us2f(u11.z);
    float v3 = w00 * us2f(u00.w) + w01 * us2f(u01.w) + w10 * us2f(u10.w) + w11 * us2f(u11.w);
    bf16 r0 = f2b(v0), r1 = f2b(v1), r2 = f2b(v2), r3 = f2b(v3);
    ushort4 o = {*(unsigned short*)&r0, *(unsigned short*)&r1,
                 *(unsigned short*)&r2, *(unsigned short*)&r3};
    *(ushort4*)((unsigned short*)f2w + ((size_t)z * 3072 + p) * 64 + g * 4) = o;
}

// ---------------------------------------------------------------------------
// MFMA conv: A staged in LDS (coalesced), B direct from frag-order global.
// 256 threads = 4 waves: wy = px-half, wx = oc-half of OC_BLK.
// Tile: MROWS*W px x OC_BLK. grid = (H/MROWS, oc-group-or-class, z).
// Barriers: 2 per ic-chunk only.
// BMODE: 0 bias fp32[OCTOT]; 1 base NHWC fp32 (2,48,64,96), b=(bd0+z)/49.
// OMODE: 0 plain NHWC bf16+ReLU; 1 parity-pack into (cnt,24,32,384);
//        2 stride-2 scatter into (cnt,48,64,32) at (2y+qy,2x+qx); 3 fp32, no ReLU.
// CLS=1 (deconv): blockIdx.y = class; wsw offset per class; taps from qy,qx.
// ---------------------------------------------------------------------------
template <int IC, int OCTOT, int OC_BLK, int H, int W, int MROWS, int NTAPS, int DXW,
          int DYLO, int DXLO, int BMODE, int OMODE, int CLS>
__global__ __launch_bounds__(256, 4) void conv_lds(const bf16* __restrict__ in_,
                                                   const bf16* __restrict__ wsw_,
                                                   const float* __restrict__ bias,
                                                   const float* __restrict__ base,
                                                   bf16* __restrict__ out, int bd0) {
    constexpr int NCH = IC / 32;
    constexpr int NfT = OC_BLK / 32;       // B frags per wave
    constexpr int MF = MROWS * W / 32;     // A frags per wave
    constexpr int TPXH = MROWS * W / 2;    // px per wy-half
    constexpr int NDY = NTAPS / DXW;
    constexpr int ROWS_IN = MROWS + NDY - 1;
    constexpr int COLS_IN = W + DXW - 1;
    constexpr int NOCF = OCTOT / 16;
    constexpr int PITCH = 40;
    __shared__ __align__(16) unsigned short s_a[ROWS_IN * COLS_IN * PITCH];

    const unsigned short* in = (const unsigned short*)in_;
    const unsigned short* wsw = (const unsigned short*)wsw_;
    const int tid = threadIdx.x;
    const int wave = tid >> 6, lane = tid & 63;
    const int m = lane & 15, q = lane >> 4;
    const int wy = wave >> 1, wx = wave & 1;
    const int bx = blockIdx.x, by = blockIdx.y, z = blockIdx.z;
    const int foff = m * PITCH + q * 8;

    int ocbase, dylo, dxlo, oqy = 0, oqx = 0;
    if constexpr (CLS == 1) {
        oqy = by >> 1; oqx = by & 1;
        dylo = oqy - 1; dxlo = oqx - 1;
        wsw += (size_t)by * NTAPS * NOCF * NCH * 512;
        ocbase = 0;
    } else {
        ocbase = by * OC_BLK;
        dylo = DYLO; dxlo = DXLO;
    }

    f32x4 acc[MF][NfT];
#pragma unroll
    for (int a = 0; a < MF; ++a)
#pragma unroll
        for (int nf = 0; nf < NfT; ++nf) acc[a][nf] = (f32x4){0.f, 0.f, 0.f, 0.f};

    for (int cc = 0; cc < NCH; ++cc) {
        constexpr int TOTA = ROWS_IN * COLS_IN * 8;
        for (int i = tid; i < TOTA; i += 256) {
            int e = i & 7;
            int pix = i >> 3;
            int cI = pix % COLS_IN;
            int r = pix / COLS_IN;
            int gy = bx * MROWS + r + dylo;
            int gx = cI + dxlo;
            ushort4 v = {0, 0, 0, 0};
            if (gy >= 0 && gy < H && gx >= 0 && gx < W)
                v = *(const ushort4*)(in + ((size_t)(z * H + gy) * W + gx) * IC + cc * 32 + e * 4);
            *(ushort4*)(&s_a[pix * PITCH + e * 4]) = v;
        }
        __syncthreads();
#pragma unroll
        for (int t = 0; t < NTAPS; ++t) {
            bf16x8 af[MF], bfr[NfT];
#pragma unroll
            for (int mf = 0; mf < MF; ++mf) {
                const int pxb = wy * TPXH + mf * 16;
                const int yl = pxb / W, xb = pxb % W;
                const unsigned short* pa =
                    &s_a[((yl + t / DXW) * COLS_IN + xb + t % DXW) * PITCH] + foff;
                af[mf] = *(const bf16x8*)pa;
            }
#pragma unroll
            for (int nf = 0; nf < NfT; ++nf) {
                const int fragoc = (ocbase >> 4) + wx * NfT + nf;
                bfr[nf] = *(const bf16x8*)(wsw + (((size_t)t * NOCF + fragoc) * NCH + cc) * 512 +
                                           lane * 8);
            }
#pragma unroll
            for (int mf = 0; mf < MF; ++mf)
#pragma unroll
                for (int nf = 0; nf < NfT; ++nf)
                    acc[mf][nf] =
                        __builtin_amdgcn_mfma_f32_16x16x32_bf16(af[mf], bfr[nf], acc[mf][nf], 0, 0, 0);
        }
        __syncthreads();
    }

    const int b = (bd0 + z) / 49;
#pragma unroll
    for (int mf = 0; mf < MF; ++mf) {
        const int pxb = wy * TPXH + mf * 16;
#pragma unroll
        for (int r = 0; r < 4; ++r) {
            const int px = pxb + q * 4 + r;
            const int yl = px / W, xl = px % W;
            const int gy = bx * MROWS + yl;
#pragma unroll
            for (int nf = 0; nf < NfT; ++nf) {
                const int oc = ocbase + wx * (OC_BLK / 2) + nf * 16 + m;
                float v = acc[mf][nf][r];
                if constexpr (BMODE == 1)
                    v += base[(((size_t)b * 48 + gy) * 64 + xl) * 96 + oc];
                else
                    v += bias[oc];
                if constexpr (OMODE == 3) {
                    ((float*)out)[(((size_t)z * H + gy) * W + xl) * OCTOT + oc] = v;
                } else {
                    v = fmaxf(v, 0.f);
                    bf16 bv = f2b(v);
                    if constexpr (OMODE == 0) {
                        out[(((size_t)z * H + gy) * W + xl) * OCTOT + oc] = bv;
                    } else if constexpr (OMODE == 1) {
                        int yy = gy >> 1, xx = xl >> 1, pp = (gy & 1) * 2 + (xl & 1);
                        out[(((size_t)z * 24 + yy) * 32 + xx) * 384 + pp * 96 + oc] = bv;
                    } else {
                        out[(((size_t)z * 48 + 2 * gy + oqy) * 64 + 2 * xl + oqx) * 32 + oc] = bv;
                    }
                }
            }
        }
    }
}

// ---------------------------------------------------------------------------
// conv5: 3x3, 32->1, no ReLU. in NHWC bf16 (cnt,48,64,32) -> cost fp32
// ---------------------------------------------------------------------------
__global__ __launch_bounds__(256) void conv5_k(const bf16* __restrict__ in_,
                                               const float* __restrict__ w5,
                                               const float* __restrict__ b5,
                                               float* __restrict__ cost, int bd0, int cnt) {
    __shared__ float s_w5[9][32];
    const int tid = threadIdx.x;
    for (int i = tid; i < 288; i += 256) {
        int ic = i % 32, t = i / 32;
        s_w5[t][ic] = w5[ic * 9 + t];
    }
    __syncthreads();
    int idx = blockIdx.x * 256 + tid;
    if (idx >= cnt * 3072) return;
    int p = idx % 3072, z = idx / 3072;
    int y = p >> 6, x = p & 63;
    const unsigned short* in = (const unsigned short*)in_;
    float acc = b5[0];
#pragma unroll
    for (int ky = 0; ky < 3; ++ky) {
        int gy = y + ky - 1;
        if (gy < 0 || gy >= 48) continue;
#pragma unroll
        for (int kx = 0; kx < 3; ++kx) {
            int gx = x + kx - 1;
            if (gx < 0 || gx >= 64) continue;
            const ushort4* src = (const ushort4*)(in + ((size_t)(z * 48 + gy) * 64 + gx) * 32);
            const float* wr = s_w5[ky * 3 + kx];
#pragma unroll
            for (int e = 0; e < 8; ++e) {
                ushort4 u = src[e];
                acc = fmaf(us2f(u.x), wr[e * 4 + 0], acc);
                acc = fmaf(us2f(u.y), wr[e * 4 + 1], acc);
                acc = fmaf(us2f(u.z), wr[e * 4 + 2], acc);
                acc = fmaf(us2f(u.w), wr[e * 4 + 3], acc);
            }
        }
    }
    cost[(size_t)(bd0 + z) * 3072 + p] = acc;
}

// ---------------------------------------------------------------------------
// DAP (49x49) + softmax + flow expectation + coords. out fp32 (2,2,48,64)
// ---------------------------------------------------------------------------
__global__ __launch_bounds__(256) void dap_flow(const float* __restrict__ cost,
                                                const float* __restrict__ wdap,
                                                const float* __restrict__ coords,
                                                float* __restrict__ outp) {
    __shared__ float s_w[49 * 49];
    int tid = threadIdx.x;
    for (int i = tid; i < 2401; i += 256) s_w[i] = wdap[i];
    __syncthreads();
    int idx = blockIdx.x * 256 + tid;
    if (idx >= 2 * 3072) return;
    int p = idx % 3072, b = idx / 3072;
    float c[49];
#pragma unroll
    for (int d = 0; d < 49; ++d) c[d] = cost[((size_t)(b * 49 + d)) * 3072 + p];
    float mx = -1e30f;
    for (int e = 0; e < 49; ++e) {
        float s = 0.f;
#pragma unroll
        for (int d = 0; d < 49; ++d) s = fmaf(s_w[e * 49 + d], c[d], s);
        mx = fmaxf(mx, s);
    }
    float sum = 0.f, sx = 0.f, sy = 0.f;
    for (int e = 0; e < 49; ++e) {
        float s = 0.f;
#pragma unroll
        for (int d = 0; d < 49; ++d) s = fmaf(s_w[e * 49 + d], c[d], s);
        float pr = __expf(s - mx);
        sum += pr;
        sx += pr * (float)(e % 7 - 3);
        sy += pr * (float)(e / 7 - 3);
    }
    float inv = 1.f / sum;
    outp[(size_t)(b * 2 + 0) * 3072 + p] = coords[(size_t)(b * 2 + 0) * 3072 + p] + sx * inv;
    outp[(size_t)(b * 2 + 1) * 3072 + p] = coords[(size_t)(b * 2 + 1) * 3072 + p] + sy * inv;
}

// ---------------------------------------------------------------------------
extern "C" void kernel_launch(void* const* d_in, const int* in_sizes, int n_in,
                              void* d_out, int out_size, void* d_ws, size_t ws_size,
                              hipStream_t stream) {
    (void)in_sizes; (void)n_in;
    const float* feat1 = (const float*)d_in[0];
    const float* feat2 = (const float*)d_in[1];
    const float* coords = (const float*)d_in[2];
    const float* w0 = (const float*)d_in[3];
    const float* b0 = (const float*)d_in[4];
    const float* w1 = (const float*)d_in[5];
    const float* b1 = (const float*)d_in[6];
    const float* w2 = (const float*)d_in[7];
    const float* b2 = (const float*)d_in[8];
    const float* w3 = (const float*)d_in[9];
    const float* b3 = (const float*)d_in[10];
    const float* wd = (const float*)d_in[11];
    const float* bdc = (const float*)d_in[12];
    const float* w5 = (const float*)d_in[13];
    const float* b5 = (const float*)d_in[14];
    const float* wdap = (const float*)d_in[15];
    float* outp = (float*)d_out;

    // workspace (fixed, same footprint as round 7):
    //  wsw0 @0 (110592) | wsw0a @110592 (110592) | wsw1 @221184 (393216)
    //  wsw2 @614400 (294912) | wsw3 @909312 (147456) | wswd @1056768 (65536)
    //  f1n @1122304 (786432) | part0 @1908736 (2359296) | cost @4268032 (1204224)
    //  f2n @5472256 (786432) | fixed_end = 6258688
    char* ws = (char*)d_ws;
    bf16* wsw0 = (bf16*)(ws + 0);
    bf16* wsw0a = (bf16*)(ws + 110592);
    bf16* wsw1 = (bf16*)(ws + 221184);
    bf16* wsw2 = (bf16*)(ws + 614400);
    bf16* wsw3 = (bf16*)(ws + 909312);
    bf16* wswd = (bf16*)(ws + 1056768);
    bf16* f1n = (bf16*)(ws + 1122304);
    float* part0 = (float*)(ws + 1908736);
    float* cost = (float*)(ws + 4268032);
    bf16* f2n = (bf16*)(ws + 5472256);
    const size_t fixed_end = 6258688;

    const int cand[7] = {98, 49, 25, 14, 7, 2, 1};
    int nb = 0;
    for (int i = 0; i < 7; ++i) {
        if (fixed_end + (size_t)983040 * cand[i] <= ws_size) { nb = cand[i]; break; }
    }
    if (nb == 0) {
        float val = 10000.f + (float)(ws_size >> 20);
        sentinel_k<<<dim3((out_size + 255) / 256), 256, 0, stream>>>(outp, out_size, val);
        return;
    }
    char* regA = ws + fixed_end;
    char* regB = regA + (size_t)393216 * nb;
    bf16* f2w = (bf16*)regA;  // (nb,48,64,64)
    bf16* x1 = (bf16*)regA;   // (nb,24,32,128)
    bf16* x3 = (bf16*)regA;   // (nb,24,32,64)
    bf16* x0p = (bf16*)regB;  // (nb,24,32,384) parity-packed
    bf16* x2 = (bf16*)regB;   // (nb,24,32,128)
    bf16* xd = (bf16*)regB;   // (nb,48,64,32)

    // packing (frag order) + transposes + part0 (once per call)
    pack_w0_sw<<<dim3(216), 256, 0, stream>>>(w0, wsw0, 64);
    pack_w0_sw<<<dim3(216), 256, 0, stream>>>(w0, wsw0a, 0);
    pack_w1_sw<<<dim3(768), 256, 0, stream>>>(w1, wsw1);
    pack_sw<128, 128, 9><<<dim3(576), 256, 0, stream>>>(w2, wsw2);
    pack_sw<64, 128, 9><<<dim3(288), 256, 0, stream>>>(w3, wsw3);
    pack_wd_sw<<<dim3(128), 256, 0, stream>>>(wd, wswd);
    to_nhwc<<<dim3(1536), 256, 0, stream>>>(feat1, f1n);
    to_nhwc<<<dim3(1536), 256, 0, stream>>>(feat2, f2n);
    // part0 = conv3x3(f1n, w0[:,:64]) + b0 -> fp32 NHWC, no ReLU
    conv_lds<64, 96, 96, 48, 64, 2, 9, 3, -1, -1, 0, 3, 0>
        <<<dim3(24, 1, 2), 256, 0, stream>>>(f1n, wsw0a, b0, nullptr, (bf16*)part0, 0);

    for (int s = 0; s < 98; s += nb) {
        int cnt = (98 - s < nb) ? (98 - s) : nb;
        warp_kernel<<<dim3(cnt * 192), 256, 0, stream>>>(f2n, coords, f2w, s, cnt);
        // conv0: IC=64 taps3x3 OC=96, base=part0, out parity-packed. 128-px tile.
        conv_lds<64, 96, 96, 48, 64, 2, 9, 3, -1, -1, 1, 1, 0>
            <<<dim3(24, 1, cnt), 256, 0, stream>>>(f2w, wsw0, nullptr, part0, x0p, s);
        // conv1: IC=384 taps{-1,0}^2 OC=128, 64-px tile, oc split 2
        conv_lds<384, 128, 64, 24, 32, 2, 4, 2, -1, -1, 0, 0, 0>
            <<<dim3(12, 2, cnt), 256, 0, stream>>>(x0p, wsw1, b1, nullptr, x1, s);
        // conv2: IC=128 taps3x3 OC=128, 64-px tile, oc split 2
        conv_lds<128, 128, 64, 24, 32, 2, 9, 3, -1, -1, 0, 0, 0>
            <<<dim3(12, 2, cnt), 256, 0, stream>>>(x1, wsw2, b2, nullptr, x2, s);
        // conv3: IC=128 taps3x3 OC=64, 64-px tile, oc split 2
        conv_lds<128, 64, 32, 24, 32, 2, 9, 3, -1, -1, 0, 0, 0>
            <<<dim3(12, 2, cnt), 256, 0, stream>>>(x2, wsw3, b3, nullptr, x3, s);
        // deconv: 4 parity classes in one launch (blockIdx.y = class), 64-px tile
        conv_lds<64, 32, 32, 24, 32, 2, 4, 2, 0, 0, 0, 2, 1>
            <<<dim3(12, 4, cnt), 256, 0, stream>>>(x3, wswd, bdc, nullptr, xd, s);
        // conv5
        conv5_k<<<dim3(cnt * 12), 256, 0, stream>>>(xd, w5, b5, cost, s, cnt);
    }

    dap_flow<<<dim3(24), 256, 0, stream>>>(cost, wdap, coords, outp);
}

// Round 9
// 415.612 us; speedup vs baseline: 1.8675x; 1.0421x over previous
//
#include <hip/hip_runtime.h>
#include <hip/hip_bf16.h>

using bf16 = __hip_bfloat16;
typedef __attribute__((ext_vector_type(8))) __bf16 bf16x8;
typedef __attribute__((ext_vector_type(4))) float f32x4;

static __device__ __forceinline__ bf16 f2b(float v) { return __float2bfloat16(v); }
static __device__ __forceinline__ float us2f(unsigned short u) {
    return __uint_as_float(((unsigned)u) << 16);
}

// Problem: B=2, C=64, H=48, W=64, D=49, BD=98. fp32 I/O.
// MFMA pipeline, NHWC bf16. 512-thr blocks, 2 images/block (wz), A in LDS,
// B pre-swizzled to MFMA frag order (global, L2-broadcast), coalesced
// epilogue via LDS transpose.

// ---------------------------------------------------------------------------
__global__ void sentinel_k(float* __restrict__ out, int nel, float val) {
    int i = blockIdx.x * 256 + threadIdx.x;
    if (i < nel) out[i] = val;
}

// ---------------------------------------------------------------------------
// Fragment-order weight packing: o = (((t*NOCF + ocf)*NCH + cc)*64 + lane)*8 + j
// lane = q*16+m; elem j = W[k=cc*32+q*8+j][oc=ocf*16+m] at tap t.
// ---------------------------------------------------------------------------
__global__ void pack_w0_sw(const float* __restrict__ w0, bf16* __restrict__ out, int icbase) {
    int o = blockIdx.x * 256 + threadIdx.x;
    if (o >= 9 * 6 * 2 * 512) return;  // T=9, NOCF=6, NCH=2
    int j = o & 7, lane = (o >> 3) & 63;
    int m = lane & 15, q = lane >> 4;
    int cc = (o >> 9) & 1;
    int fragid = o >> 10;
    int t = fragid / 6, ocf = fragid % 6;
    int oc = ocf * 16 + m, ic = cc * 32 + q * 8 + j;
    out[o] = f2b(w0[((size_t)oc * 128 + icbase + ic) * 9 + t]);
}

template <int OC, int IC, int T>
__global__ void pack_sw(const float* __restrict__ w, bf16* __restrict__ out) {
    constexpr int NOCF = OC / 16, NCH = IC / 32;
    int o = blockIdx.x * 256 + threadIdx.x;
    if (o >= T * NOCF * NCH * 512) return;
    int j = o & 7, lane = (o >> 3) & 63;
    int m = lane & 15, q = lane >> 4;
    int cc = (o >> 9) % NCH;
    int fragid = (o >> 9) / NCH;
    int t = fragid / NOCF, ocf = fragid % NOCF;
    int oc = ocf * 16 + m, ic = cc * 32 + q * 8 + j;
    out[o] = f2b(w[((size_t)oc * IC + ic) * T + t]);
}

// conv1 parity-plane weights, frag order. T=4 (t2), OC=128, IC=384.
__global__ void pack_w1_sw(const float* __restrict__ w1, bf16* __restrict__ out) {
    int o = blockIdx.x * 256 + threadIdx.x;
    if (o >= 4 * 8 * 12 * 512) return;  // NOCF=8, NCH=12
    int j = o & 7, lane = (o >> 3) & 63;
    int m = lane & 15, q = lane >> 4;
    int cc = (o >> 9) % 12;
    int fragid = (o >> 9) / 12;
    int t2 = fragid / 8, ocf = fragid % 8;
    int oc = ocf * 16 + m;
    int pc = cc * 32 + q * 8 + j;
    int dy = (t2 < 2) ? -1 : 0;
    int dx = (t2 & 1) ? 0 : -1;
    int p = pc / 96, ic = pc % 96;
    int py = p >> 1, px = p & 1;
    int ky = (dy == -1) ? (py == 1 ? 0 : -1) : (py == 0 ? 1 : 2);
    int kx = (dx == -1) ? (px == 1 ? 0 : -1) : (px == 0 ? 1 : 2);
    float v = (ky >= 0 && kx >= 0) ? w1[((size_t)oc * 96 + ic) * 9 + ky * 3 + kx] : 0.f;
    out[o] = f2b(v);
}

// deconv class weights, frag order: 4 classes x (T=4, NOCF=2, NCH=2).
__global__ void pack_wd_sw(const float* __restrict__ wd, bf16* __restrict__ out) {
    int o = blockIdx.x * 256 + threadIdx.x;
    if (o >= 4 * 4 * 2 * 2 * 512) return;
    int j = o & 7, lane = (o >> 3) & 63;
    int m = lane & 15, q = lane >> 4;
    int cc = (o >> 9) & 1;
    int ocf = (o >> 10) & 1;
    int t2 = (o >> 11) & 3;
    int c = o >> 13;
    int oc = ocf * 16 + m, ic = cc * 32 + q * 8 + j;
    int qy = c >> 1, qx = c & 1;
    int dy = qy - 1 + (t2 >> 1), dx = qx - 1 + (t2 & 1);
    int ky = (qy == 0) ? (dy == -1 ? 0 : 2) : (dy == 0 ? 1 : 3);
    int kx = (qx == 0) ? (dx == -1 ? 0 : 2) : (dx == 0 ? 1 : 3);
    out[o] = f2b(wd[((size_t)oc * 64 + ic) * 16 + ky * 4 + kx]);
}

// ---------------------------------------------------------------------------
// NCHW fp32 (2,64,48,64) -> NHWC bf16 (2,48,64,64)
// ---------------------------------------------------------------------------
__global__ void to_nhwc(const float* __restrict__ src, bf16* __restrict__ dst) {
    int i = blockIdx.x * 256 + threadIdx.x;
    if (i >= 2 * 3072 * 64) return;
    int c = i & 63;
    int p = (i >> 6) % 3072;
    int b = i / (3072 * 64);
    dst[i] = f2b(src[((size_t)b * 64 + c) * 3072 + p]);
}

// ---------------------------------------------------------------------------
// warp: bilinear from f2n (NHWC bf16). thread = (pixel, 4-channel group).
// ---------------------------------------------------------------------------
__global__ __launch_bounds__(256) void warp_kernel(const bf16* __restrict__ f2n,
                                                   const float* __restrict__ coords,
                                                   bf16* __restrict__ f2w, int bd0, int cnt) {
    int idx = blockIdx.x * 256 + threadIdx.x;
    if (idx >= cnt * 3072 * 16) return;
    int g = idx & 15;
    int pix = idx >> 4;
    int p = pix % 3072;
    int z = pix / 3072;
    int bd = bd0 + z;
    int b = bd / 49, d = bd % 49;
    float du = (float)(d % 7 - 3), dv = (float)(d / 7 - 3);
    float cx = coords[(size_t)(b * 2 + 0) * 3072 + p] + du;
    float cy = coords[(size_t)(b * 2 + 1) * 3072 + p] + dv;
    float x0f = floorf(cx), y0f = floorf(cy);
    float wx = cx - x0f, wy = cy - y0f;
    int x0 = (int)x0f, y0 = (int)y0f;
    int x1 = x0 + 1, y1 = y0 + 1;
    bool vx0 = (x0 >= 0) && (x0 < 64), vx1 = (x1 >= 0) && (x1 < 64);
    bool vy0 = (y0 >= 0) && (y0 < 48), vy1 = (y1 >= 0) && (y1 < 48);
    int xc0 = min(max(x0, 0), 63), xc1 = min(max(x1, 0), 63);
    int yc0 = min(max(y0, 0), 47), yc1 = min(max(y1, 0), 47);
    float w00 = (vx0 && vy0) ? (1.f - wx) * (1.f - wy) : 0.f;
    float w01 = (vx1 && vy0) ? wx * (1.f - wy) : 0.f;
    float w10 = (vx0 && vy1) ? (1.f - wx) * wy : 0.f;
    float w11 = (vx1 && vy1) ? wx * wy : 0.f;
    const unsigned short* f2 = (const unsigned short*)f2n + (size_t)b * 3072 * 64 + g * 4;
    ushort4 u00 = *(const ushort4*)(f2 + (size_t)(yc0 * 64 + xc0) * 64);
    ushort4 u01 = *(const ushort4*)(f2 + (size_t)(yc0 * 64 + xc1) * 64);
    ushort4 u10 = *(const ushort4*)(f2 + (size_t)(yc1 * 64 + xc0) * 64);
    ushort4 u11 = *(const ushort4*)(f2 + (size_t)(yc1 * 64 + xc1) * 64);
    float v0 = w00 * us2f(u00.x) + w01 * us2f(u01.x) + w10 * us2f(u10.x) + w11 * us2f(u11.x);
    float v1 = w00 * us2f(u00.y) + w01 * us2f(u01.y) + w10 * us2f(u10.y) + w11 * us2f(u11.y);
    float v2 = w00 * us2f(u00.z) + w01 * us2f(u01.z) + w10 * us2f(u10.z) + w11 * us2f(u11.z);
    float v3 = w00 * us2f(u00.w) + w01 * us2f(u01.w) + w10 * us2f(u10.w) + w11 * us2f(u11.w);
    bf16 r0 = f2b(v0), r1 = f2b(v1), r2 = f2b(v2), r3 = f2b(v3);
    ushort4 o = {*(unsigned short*)&r0, *(unsigned short*)&r1,
                 *(unsigned short*)&r2, *(unsigned short*)&r3};
    *(ushort4*)((unsigned short*)f2w + ((size_t)z * 3072 + p) * 64 + g * 4) = o;
}

// ---------------------------------------------------------------------------
// 512-thread MFMA conv, 2 images per block. waves: (wz, wy, wx).
// A staged in LDS per (z, ic-chunk); B direct from frag-order global.
// BMODE: 0 bias fp32[OCTOT]; 1 base NHWC bf16 (2,48,64,96), b=(bd0+z)/49.
// OMODE: 0 NHWC bf16+ReLU (LDS-transposed coalesced); 1 parity-pack (transposed);
//        2 stride-2 scatter (64B segs, deconv); 4 NHWC bf16 NO ReLU (transposed).
// CLS=1 (deconv): blockIdx.y = class; wsw offset per class; taps from qy,qx.
// ---------------------------------------------------------------------------
template <int IC, int OCTOT, int OC_BLK, int H, int W, int MROWS, int NTAPS, int DXW,
          int DYLO, int DXLO, int BMODE, int OMODE, int CLS>
__global__ __launch_bounds__(512, 4) void conv_ldz(const bf16* __restrict__ in_,
                                                   const bf16* __restrict__ wsw_,
                                                   const float* __restrict__ bias,
                                                   const bf16* __restrict__ base_,
                                                   bf16* __restrict__ out, int bd0, int cnt) {
    constexpr int NCH = IC / 32;
    constexpr int NfT = OC_BLK / 32;       // B frags per wave (wx half)
    constexpr int TPXH = MROWS * W / 2;    // px per wy-half
    constexpr int MF = TPXH / 16;          // A frags per wave
    constexpr int NDY = NTAPS / DXW;
    constexpr int ROWS_IN = MROWS + NDY - 1;
    constexpr int COLS_IN = W + DXW - 1;
    constexpr int NOCF = OCTOT / 16;
    constexpr int PITCH = 40;
    constexpr int SZA = ROWS_IN * COLS_IN * PITCH;  // shorts per (z,cc)
    constexpr int OUTSH = (OMODE != 2) ? MROWS * W * OC_BLK : 0;
    constexpr int SMEM = (2 * SZA > OUTSH) ? 2 * SZA : OUTSH;
    __shared__ __align__(16) unsigned short s_mem[SMEM];

    const unsigned short* in = (const unsigned short*)in_;
    const unsigned short* wsw = (const unsigned short*)wsw_;
    const unsigned short* baseh = (const unsigned short*)base_;
    const int tid = threadIdx.x;
    const int wave = tid >> 6, lane = tid & 63;
    const int m = lane & 15, q = lane >> 4;
    const int wz = wave >> 2, wy = (wave >> 1) & 1, wx = wave & 1;
    const int bx = blockIdx.x, by = blockIdx.y;
    const int z0 = blockIdx.z * 2;
    const int zw = z0 + wz;                 // this wave's image
    const bool zok = zw < cnt;
    const int foff = m * PITCH + q * 8;

    int ocbase, dylo, dxlo, oqy = 0, oqx = 0;
    if constexpr (CLS == 1) {
        oqy = by >> 1; oqx = by & 1;
        dylo = oqy - 1; dxlo = oqx - 1;
        wsw += (size_t)by * NTAPS * NOCF * NCH * 512;
        ocbase = 0;
    } else {
        ocbase = by * OC_BLK;
        dylo = DYLO; dxlo = DXLO;
    }

    f32x4 acc[MF][NfT];
#pragma unroll
    for (int a = 0; a < MF; ++a)
#pragma unroll
        for (int nf = 0; nf < NfT; ++nf) acc[a][nf] = (f32x4){0.f, 0.f, 0.f, 0.f};

    for (int cc = 0; cc < NCH; ++cc) {
        constexpr int SZE = ROWS_IN * COLS_IN * 8;
        for (int i = tid; i < 2 * SZE; i += 512) {
            int zz = i / SZE;
            int r2 = i % SZE;
            int e = r2 & 7;
            int pix = r2 >> 3;
            int cI = pix % COLS_IN;
            int rr = pix / COLS_IN;
            int gy = bx * MROWS + rr + dylo;
            int gx = cI + dxlo;
            ushort4 v = {0, 0, 0, 0};
            if ((z0 + zz) < cnt && gy >= 0 && gy < H && gx >= 0 && gx < W)
                v = *(const ushort4*)(in +
                                      ((size_t)((z0 + zz) * H + gy) * W + gx) * IC + cc * 32 + e * 4);
            *(ushort4*)(&s_mem[zz * SZA + pix * PITCH + e * 4]) = v;
        }
        __syncthreads();
        if (zok) {
#pragma unroll
            for (int t = 0; t < NTAPS; ++t) {
                bf16x8 af[MF], bfr[NfT];
#pragma unroll
                for (int mf = 0; mf < MF; ++mf) {
                    const int pxb = wy * TPXH + mf * 16;
                    const int yl = pxb / W, xb = pxb % W;
                    const unsigned short* pa =
                        &s_mem[wz * SZA + ((yl + t / DXW) * COLS_IN + xb + t % DXW) * PITCH] + foff;
                    af[mf] = *(const bf16x8*)pa;
                }
#pragma unroll
                for (int nf = 0; nf < NfT; ++nf) {
                    const int fragoc = (ocbase >> 4) + wx * NfT + nf;
                    bfr[nf] = *(const bf16x8*)(wsw +
                                               (((size_t)t * NOCF + fragoc) * NCH + cc) * 512 +
                                               lane * 8);
                }
#pragma unroll
                for (int mf = 0; mf < MF; ++mf)
#pragma unroll
                    for (int nf = 0; nf < NfT; ++nf)
                        acc[mf][nf] = __builtin_amdgcn_mfma_f32_16x16x32_bf16(af[mf], bfr[nf],
                                                                              acc[mf][nf], 0, 0, 0);
            }
        }
        __syncthreads();
    }

    if constexpr (OMODE == 2) {
        // deconv scatter: 64B contiguous segments per (px)
        if (zok) {
            const float bb = bias[ocbase + wx * 16 + m];
#pragma unroll
            for (int mf = 0; mf < MF; ++mf) {
                const int pxb = wy * TPXH + mf * 16;
#pragma unroll
                for (int r = 0; r < 4; ++r) {
                    const int px = pxb + q * 4 + r;
                    const int yl = px / W, xl = px % W;
                    const int gy = bx * MROWS + yl;
                    float v = fmaxf(acc[mf][0][r] + bb, 0.f);
                    out[(((size_t)zw * 48 + 2 * gy + oqy) * 64 + 2 * xl + oqx) * 32 + wx * 16 + m] =
                        f2b(v);
                }
            }
        }
    } else {
        // transposed coalesced epilogue
        const int bimg = (bd0 + zw) / 49;
        float bb[NfT];
        if constexpr (BMODE == 0) {
#pragma unroll
            for (int nf = 0; nf < NfT; ++nf)
                bb[nf] = bias[ocbase + wx * (OC_BLK / 2) + nf * 16 + m];
        }
        for (int zz = 0; zz < 2; ++zz) {
            if (wz == zz && zok) {
#pragma unroll
                for (int mf = 0; mf < MF; ++mf) {
                    const int pxb = wy * TPXH + mf * 16;
#pragma unroll
                    for (int r = 0; r < 4; ++r) {
                        const int px = pxb + q * 4 + r;
                        const int yl = px / W, xl = px % W;
                        const int gy = bx * MROWS + yl;
#pragma unroll
                        for (int nf = 0; nf < NfT; ++nf) {
                            const int oc = wx * (OC_BLK / 2) + nf * 16 + m;
                            float v = acc[mf][nf][r];
                            if constexpr (BMODE == 1)
                                v += us2f(baseh[(((size_t)bimg * 48 + gy) * 64 + xl) * 96 +
                                                ocbase + oc]);
                            else
                                v += bb[nf];
                            if constexpr (OMODE != 4) v = fmaxf(v, 0.f);
                            bf16 bv = f2b(v);
                            s_mem[px * OC_BLK + oc] = *(unsigned short*)&bv;
                        }
                    }
                }
            }
            __syncthreads();
            const int z = z0 + zz;
            if (z < cnt) {
                constexpr int TOT16 = MROWS * W * OC_BLK / 8;
                for (int g = tid; g < TOT16; g += 512) {
                    const int o = g * 8;
                    uint4 vv = *(const uint4*)&s_mem[o];
                    if constexpr (OMODE == 1) {
                        // parity pack: MROWS==2, W==64, OC_BLK==96
                        const int xx = o / 384;
                        const int rr = o % 384;
                        const int pp = rr / 96;
                        const int oco = rr % 96;
                        const int px = (pp >> 1) * 64 + 2 * xx + (pp & 1);
                        vv = *(const uint4*)&s_mem[px * 96 + oco];
                        *(uint4*)((unsigned short*)out +
                                  (((size_t)z * 24 + bx) * 32 + xx) * 384 + rr) = vv;
                    } else {
                        const int px = o / OC_BLK;
                        const int oco = o % OC_BLK;
                        const int gy = bx * MROWS + px / W;
                        const int xl = px % W;
                        *(uint4*)((unsigned short*)out +
                                  (((size_t)z * H + gy) * W + xl) * OCTOT + ocbase + oco) = vv;
                    }
                }
            }
            __syncthreads();
        }
    }
}

// ---------------------------------------------------------------------------
// conv5: 3x3, 32->1, no ReLU. in NHWC bf16 (cnt,48,64,32) -> cost fp32
// ---------------------------------------------------------------------------
__global__ __launch_bounds__(256) void conv5_k(const bf16* __restrict__ in_,
                                               const float* __restrict__ w5,
                                               const float* __restrict__ b5,
                                               float* __restrict__ cost, int bd0, int cnt) {
    __shared__ float s_w5[9][32];
    const int tid = threadIdx.x;
    for (int i = tid; i < 288; i += 256) {
        int ic = i % 32, t = i / 32;
        s_w5[t][ic] = w5[ic * 9 + t];
    }
    __syncthreads();
    int idx = blockIdx.x * 256 + tid;
    if (idx >= cnt * 3072) return;
    int p = idx % 3072, z = idx / 3072;
    int y = p >> 6, x = p & 63;
    const unsigned short* in = (const unsigned short*)in_;
    float acc = b5[0];
#pragma unroll
    for (int ky = 0; ky < 3; ++ky) {
        int gy = y + ky - 1;
        if (gy < 0 || gy >= 48) continue;
#pragma unroll
        for (int kx = 0; kx < 3; ++kx) {
            int gx = x + kx - 1;
            if (gx < 0 || gx >= 64) continue;
            const ushort4* src = (const ushort4*)(in + ((size_t)(z * 48 + gy) * 64 + gx) * 32);
            const float* wr = s_w5[ky * 3 + kx];
#pragma unroll
            for (int e = 0; e < 8; ++e) {
                ushort4 u = src[e];
                acc = fmaf(us2f(u.x), wr[e * 4 + 0], acc);
                acc = fmaf(us2f(u.y), wr[e * 4 + 1], acc);
                acc = fmaf(us2f(u.z), wr[e * 4 + 2], acc);
                acc = fmaf(us2f(u.w), wr[e * 4 + 3], acc);
            }
        }
    }
    cost[(size_t)(bd0 + z) * 3072 + p] = acc;
}

// ---------------------------------------------------------------------------
// DAP (49x49) + softmax + flow expectation + coords. out fp32 (2,2,48,64)
// ---------------------------------------------------------------------------
__global__ __launch_bounds__(256) void dap_flow(const float* __restrict__ cost,
                                                const float* __restrict__ wdap,
                                                const float* __restrict__ coords,
                                                float* __restrict__ outp) {
    __shared__ float s_w[49 * 49];
    int tid = threadIdx.x;
    for (int i = tid; i < 2401; i += 256) s_w[i] = wdap[i];
    __syncthreads();
    int idx = blockIdx.x * 256 + tid;
    if (idx >= 2 * 3072) return;
    int p = idx % 3072, b = idx / 3072;
    float c[49];
#pragma unroll
    for (int d = 0; d < 49; ++d) c[d] = cost[((size_t)(b * 49 + d)) * 3072 + p];
    float mx = -1e30f;
    for (int e = 0; e < 49; ++e) {
        float s = 0.f;
#pragma unroll
        for (int d = 0; d < 49; ++d) s = fmaf(s_w[e * 49 + d], c[d], s);
        mx = fmaxf(mx, s);
    }
    float sum = 0.f, sx = 0.f, sy = 0.f;
    for (int e = 0; e < 49; ++e) {
        float s = 0.f;
#pragma unroll
        for (int d = 0; d < 49; ++d) s = fmaf(s_w[e * 49 + d], c[d], s);
        float pr = __expf(s - mx);
        sum += pr;
        sx += pr * (float)(e % 7 - 3);
        sy += pr * (float)(e / 7 - 3);
    }
    float inv = 1.f / sum;
    outp[(size_t)(b * 2 + 0) * 3072 + p] = coords[(size_t)(b * 2 + 0) * 3072 + p] + sx * inv;
    outp[(size_t)(b * 2 + 1) * 3072 + p] = coords[(size_t)(b * 2 + 1) * 3072 + p] + sy * inv;
}

// ---------------------------------------------------------------------------
extern "C" void kernel_launch(void* const* d_in, const int* in_sizes, int n_in,
                              void* d_out, int out_size, void* d_ws, size_t ws_size,
                              hipStream_t stream) {
    (void)in_sizes; (void)n_in;
    const float* feat1 = (const float*)d_in[0];
    const float* feat2 = (const float*)d_in[1];
    const float* coords = (const float*)d_in[2];
    const float* w0 = (const float*)d_in[3];
    const float* b0 = (const float*)d_in[4];
    const float* w1 = (const float*)d_in[5];
    const float* b1 = (const float*)d_in[6];
    const float* w2 = (const float*)d_in[7];
    const float* b2 = (const float*)d_in[8];
    const float* w3 = (const float*)d_in[9];
    const float* b3 = (const float*)d_in[10];
    const float* wd = (const float*)d_in[11];
    const float* bdc = (const float*)d_in[12];
    const float* w5 = (const float*)d_in[13];
    const float* b5 = (const float*)d_in[14];
    const float* wdap = (const float*)d_in[15];
    float* outp = (float*)d_out;

    // workspace (fixed):
    //  wsw0 @0 (110592) | wsw0a @110592 (110592) | wsw1 @221184 (393216)
    //  wsw2 @614400 (294912) | wsw3 @909312 (147456) | wswd @1056768 (65536)
    //  f1n @1122304 (786432) | part0(bf16) @1908736 (1179648) | cost @3088384 (1204224)
    //  f2n @4292608 (786432) | fixed_end = 5079040
    char* ws = (char*)d_ws;
    bf16* wsw0 = (bf16*)(ws + 0);
    bf16* wsw0a = (bf16*)(ws + 110592);
    bf16* wsw1 = (bf16*)(ws + 221184);
    bf16* wsw2 = (bf16*)(ws + 614400);
    bf16* wsw3 = (bf16*)(ws + 909312);
    bf16* wswd = (bf16*)(ws + 1056768);
    bf16* f1n = (bf16*)(ws + 1122304);
    bf16* part0 = (bf16*)(ws + 1908736);
    float* cost = (float*)(ws + 3088384);
    bf16* f2n = (bf16*)(ws + 4292608);
    const size_t fixed_end = 5079040;

    const int cand[7] = {98, 49, 25, 14, 7, 2, 1};
    int nb = 0;
    for (int i = 0; i < 7; ++i) {
        if (fixed_end + (size_t)983040 * cand[i] <= ws_size) { nb = cand[i]; break; }
    }
    if (nb == 0) {
        float val = 10000.f + (float)(ws_size >> 20);
        sentinel_k<<<dim3((out_size + 255) / 256), 256, 0, stream>>>(outp, out_size, val);
        return;
    }
    char* regA = ws + fixed_end;
    char* regB = regA + (size_t)393216 * nb;
    bf16* f2w = (bf16*)regA;  // (nb,48,64,64)
    bf16* x1 = (bf16*)regA;   // (nb,24,32,128)
    bf16* x3 = (bf16*)regA;   // (nb,24,32,64)
    bf16* x0p = (bf16*)regB;  // (nb,24,32,384) parity-packed
    bf16* x2 = (bf16*)regB;   // (nb,24,32,128)
    bf16* xd = (bf16*)regB;   // (nb,48,64,32)

    // packing + transposes + part0 (once per call)
    pack_w0_sw<<<dim3(216), 256, 0, stream>>>(w0, wsw0, 64);
    pack_w0_sw<<<dim3(216), 256, 0, stream>>>(w0, wsw0a, 0);
    pack_w1_sw<<<dim3(768), 256, 0, stream>>>(w1, wsw1);
    pack_sw<128, 128, 9><<<dim3(576), 256, 0, stream>>>(w2, wsw2);
    pack_sw<64, 128, 9><<<dim3(288), 256, 0, stream>>>(w3, wsw3);
    pack_wd_sw<<<dim3(128), 256, 0, stream>>>(wd, wswd);
    to_nhwc<<<dim3(1536), 256, 0, stream>>>(feat1, f1n);
    to_nhwc<<<dim3(1536), 256, 0, stream>>>(feat2, f2n);
    // part0 = conv3x3(f1n, w0[:,:64]) + b0 -> bf16 NHWC (2,48,64,96), no ReLU
    conv_ldz<64, 96, 96, 48, 64, 2, 9, 3, -1, -1, 0, 4, 0>
        <<<dim3(24, 1, 1), 512, 0, stream>>>(f1n, wsw0a, b0, nullptr, part0, 0, 2);

    for (int s = 0; s < 98; s += nb) {
        int cnt = (98 - s < nb) ? (98 - s) : nb;
        int zp = (cnt + 1) / 2;
        warp_kernel<<<dim3(cnt * 192), 256, 0, stream>>>(f2n, coords, f2w, s, cnt);
        // conv0: IC=64 taps3x3 OC=96, base=part0(bf16), parity-pack out
        conv_ldz<64, 96, 96, 48, 64, 2, 9, 3, -1, -1, 1, 1, 0>
            <<<dim3(24, 1, zp), 512, 0, stream>>>(f2w, wsw0, nullptr, part0, x0p, s, cnt);
        // conv1: IC=384 taps{-1,0}^2 OC=128, 128px tile, oc split 2
        conv_ldz<384, 128, 64, 24, 32, 4, 4, 2, -1, -1, 0, 0, 0>
            <<<dim3(6, 2, zp), 512, 0, stream>>>(x0p, wsw1, b1, nullptr, x1, s, cnt);
        // conv2: IC=128 taps3x3 OC=128, 128px tile, oc split 2
        conv_ldz<128, 128, 64, 24, 32, 4, 9, 3, -1, -1, 0, 0, 0>
            <<<dim3(6, 2, zp), 512, 0, stream>>>(x1, wsw2, b2, nullptr, x2, s, cnt);
        // conv3: IC=128 taps3x3 OC=64, 128px tile, oc split 2
        conv_ldz<128, 64, 32, 24, 32, 4, 9, 3, -1, -1, 0, 0, 0>
            <<<dim3(6, 2, zp), 512, 0, stream>>>(x2, wsw3, b3, nullptr, x3, s, cnt);
        // deconv: 4 parity classes (blockIdx.y), 128px tile, scatter 64B segs
        conv_ldz<64, 32, 32, 24, 32, 4, 4, 2, 0, 0, 0, 2, 1>
            <<<dim3(6, 4, zp), 512, 0, stream>>>(x3, wswd, bdc, nullptr, xd, s, cnt);
        // conv5
        conv5_k<<<dim3(cnt * 12), 256, 0, stream>>>(xd, w5, b5, cost, s, cnt);
    }

    dap_flow<<<dim3(24), 256, 0, stream>>>(cost, wdap, coords, outp);
}

// Round 10
// 389.832 us; speedup vs baseline: 1.9910x; 1.0661x over previous
//
#include <hip/hip_runtime.h>
#include <hip/hip_bf16.h>

using bf16 = __hip_bfloat16;
typedef __attribute__((ext_vector_type(8))) __bf16 bf16x8;
typedef __attribute__((ext_vector_type(4))) float f32x4;

static __device__ __forceinline__ bf16 f2b(float v) { return __float2bfloat16(v); }
static __device__ __forceinline__ float us2f(unsigned short u) {
    return __uint_as_float(((unsigned)u) << 16);
}

// Problem: B=2, C=64, H=48, W=64, D=49, BD=98. fp32 I/O.
// MFMA pipeline, NHWC bf16. 512-thr blocks, 2 images/block, A in LDS (uint4
// staging), B pre-swizzled frag-order global with DOUBLE-BUFFERED prefetch,
// coalesced LDS-transpose epilogues. Deconv = single merged 4-class kernel.

// ---------------------------------------------------------------------------
__global__ void sentinel_k(float* __restrict__ out, int nel, float val) {
    int i = blockIdx.x * 256 + threadIdx.x;
    if (i < nel) out[i] = val;
}

// ---------------------------------------------------------------------------
// All weight packs in ONE launch. Frag-order layout:
// o = (((t*NOCF + ocf)*NCH + cc)*64 + lane)*8 + j ; lane=q*16+m
// elem j = W[k=cc*32+q*8+j][oc=ocf*16+m] at tap t.
// segments: wsw0 [0,55296) | wsw0a [55296,110592) | wsw1 [110592,307200)
//           wsw2 [307200,454656) | wsw3 [454656,528384) | wswd [528384,561152)
// ---------------------------------------------------------------------------
__global__ void pack_all(const float* __restrict__ w0, const float* __restrict__ w1,
                         const float* __restrict__ w2, const float* __restrict__ w3,
                         const float* __restrict__ wd, bf16* __restrict__ wsw0,
                         bf16* __restrict__ wsw0a, bf16* __restrict__ wsw1,
                         bf16* __restrict__ wsw2, bf16* __restrict__ wsw3,
                         bf16* __restrict__ wswd) {
    int i = blockIdx.x * 256 + threadIdx.x;
    if (i < 110592) {
        // w0 halves: T=9, NOCF=6, NCH=2
        int icbase = (i < 55296) ? 64 : 0;
        bf16* dst = (i < 55296) ? wsw0 : wsw0a;
        int o = (i < 55296) ? i : i - 55296;
        int j = o & 7, lane = (o >> 3) & 63;
        int m = lane & 15, q = lane >> 4;
        int cc = (o >> 9) & 1;
        int fragid = o >> 10;
        int t = fragid / 6, ocf = fragid % 6;
        int oc = ocf * 16 + m, ic = cc * 32 + q * 8 + j;
        dst[o] = f2b(w0[((size_t)oc * 128 + icbase + ic) * 9 + t]);
    } else if (i < 307200) {
        // conv1 parity weights: T=4(t2), NOCF=8, NCH=12
        int o = i - 110592;
        int j = o & 7, lane = (o >> 3) & 63;
        int m = lane & 15, q = lane >> 4;
        int cc = (o >> 9) % 12;
        int fragid = (o >> 9) / 12;
        int t2 = fragid / 8, ocf = fragid % 8;
        int oc = ocf * 16 + m;
        int pc = cc * 32 + q * 8 + j;
        int dy = (t2 < 2) ? -1 : 0;
        int dx = (t2 & 1) ? 0 : -1;
        int p = pc / 96, ic = pc % 96;
        int py = p >> 1, px = p & 1;
        int ky = (dy == -1) ? (py == 1 ? 0 : -1) : (py == 0 ? 1 : 2);
        int kx = (dx == -1) ? (px == 1 ? 0 : -1) : (px == 0 ? 1 : 2);
        float v = (ky >= 0 && kx >= 0) ? w1[((size_t)oc * 96 + ic) * 9 + ky * 3 + kx] : 0.f;
        wsw1[o] = f2b(v);
    } else if (i < 454656) {
        // w2: T=9, OC=128, IC=128 -> NOCF=8, NCH=4
        int o = i - 307200;
        int j = o & 7, lane = (o >> 3) & 63;
        int m = lane & 15, q = lane >> 4;
        int cc = (o >> 9) % 4;
        int fragid = (o >> 9) / 4;
        int t = fragid / 8, ocf = fragid % 8;
        int oc = ocf * 16 + m, ic = cc * 32 + q * 8 + j;
        wsw2[o] = f2b(w2[((size_t)oc * 128 + ic) * 9 + t]);
    } else if (i < 528384) {
        // w3: T=9, OC=64, IC=128 -> NOCF=4, NCH=4
        int o = i - 454656;
        int j = o & 7, lane = (o >> 3) & 63;
        int m = lane & 15, q = lane >> 4;
        int cc = (o >> 9) % 4;
        int fragid = (o >> 9) / 4;
        int t = fragid / 4, ocf = fragid % 4;
        int oc = ocf * 16 + m, ic = cc * 32 + q * 8 + j;
        wsw3[o] = f2b(w3[((size_t)oc * 128 + ic) * 9 + t]);
    } else if (i < 561152) {
        // deconv: 4 classes x (T=4, NOCF=2, NCH=2)
        int o = i - 528384;
        int j = o & 7, lane = (o >> 3) & 63;
        int m = lane & 15, q = lane >> 4;
        int cc = (o >> 9) & 1;
        int ocf = (o >> 10) & 1;
        int t2 = (o >> 11) & 3;
        int c = o >> 13;
        int oc = ocf * 16 + m, ic = cc * 32 + q * 8 + j;
        int qy = c >> 1, qx = c & 1;
        int dy = qy - 1 + (t2 >> 1), dx = qx - 1 + (t2 & 1);
        int ky = (qy == 0) ? (dy == -1 ? 0 : 2) : (dy == 0 ? 1 : 3);
        int kx = (qx == 0) ? (dx == -1 ? 0 : 2) : (dx == 0 ? 1 : 3);
        wswd[o] = f2b(wd[((size_t)oc * 64 + ic) * 16 + ky * 4 + kx]);
    }
}

// ---------------------------------------------------------------------------
// feat1+feat2 NCHW fp32 -> NHWC bf16, one launch
// ---------------------------------------------------------------------------
__global__ void to_nhwc2(const float* __restrict__ feat1, const float* __restrict__ feat2,
                         bf16* __restrict__ f1n, bf16* __restrict__ f2n) {
    int i = blockIdx.x * 256 + threadIdx.x;
    const float* src = (i < 393216) ? feat1 : feat2;
    bf16* dst = (i < 393216) ? f1n : f2n;
    int o = (i < 393216) ? i : i - 393216;
    if (o >= 393216) return;
    int c = o & 63;
    int p = (o >> 6) % 3072;
    int b = o / (3072 * 64);
    dst[o] = f2b(src[((size_t)b * 64 + c) * 3072 + p]);
}

// ---------------------------------------------------------------------------
// warp: bilinear from f2n (NHWC bf16). thread = (pixel, 8-channel group), 16B.
// ---------------------------------------------------------------------------
__global__ __launch_bounds__(256) void warp_kernel(const bf16* __restrict__ f2n,
                                                   const float* __restrict__ coords,
                                                   bf16* __restrict__ f2w, int bd0, int cnt) {
    int idx = blockIdx.x * 256 + threadIdx.x;
    if (idx >= cnt * 3072 * 8) return;
    int g = idx & 7;
    int pix = idx >> 3;
    int p = pix % 3072;
    int z = pix / 3072;
    int bd = bd0 + z;
    int b = bd / 49, d = bd % 49;
    float du = (float)(d % 7 - 3), dv = (float)(d / 7 - 3);
    float cx = coords[(size_t)(b * 2 + 0) * 3072 + p] + du;
    float cy = coords[(size_t)(b * 2 + 1) * 3072 + p] + dv;
    float x0f = floorf(cx), y0f = floorf(cy);
    float wx = cx - x0f, wy = cy - y0f;
    int x0 = (int)x0f, y0 = (int)y0f;
    int x1 = x0 + 1, y1 = y0 + 1;
    bool vx0 = (x0 >= 0) && (x0 < 64), vx1 = (x1 >= 0) && (x1 < 64);
    bool vy0 = (y0 >= 0) && (y0 < 48), vy1 = (y1 >= 0) && (y1 < 48);
    int xc0 = min(max(x0, 0), 63), xc1 = min(max(x1, 0), 63);
    int yc0 = min(max(y0, 0), 47), yc1 = min(max(y1, 0), 47);
    float w00 = (vx0 && vy0) ? (1.f - wx) * (1.f - wy) : 0.f;
    float w01 = (vx1 && vy0) ? wx * (1.f - wy) : 0.f;
    float w10 = (vx0 && vy1) ? (1.f - wx) * wy : 0.f;
    float w11 = (vx1 && vy1) ? wx * wy : 0.f;
    const unsigned short* f2 = (const unsigned short*)f2n + (size_t)b * 3072 * 64 + g * 8;
    ushort4 a0 = *(const ushort4*)(f2 + (size_t)(yc0 * 64 + xc0) * 64);
    ushort4 a1 = *(const ushort4*)(f2 + (size_t)(yc0 * 64 + xc0) * 64 + 4);
    ushort4 b0v = *(const ushort4*)(f2 + (size_t)(yc0 * 64 + xc1) * 64);
    ushort4 b1v = *(const ushort4*)(f2 + (size_t)(yc0 * 64 + xc1) * 64 + 4);
    ushort4 c0 = *(const ushort4*)(f2 + (size_t)(yc1 * 64 + xc0) * 64);
    ushort4 c1 = *(const ushort4*)(f2 + (size_t)(yc1 * 64 + xc0) * 64 + 4);
    ushort4 d0 = *(const ushort4*)(f2 + (size_t)(yc1 * 64 + xc1) * 64);
    ushort4 d1 = *(const ushort4*)(f2 + (size_t)(yc1 * 64 + xc1) * 64 + 4);
    unsigned short ua[8] = {a0.x, a0.y, a0.z, a0.w, a1.x, a1.y, a1.z, a1.w};
    unsigned short ub[8] = {b0v.x, b0v.y, b0v.z, b0v.w, b1v.x, b1v.y, b1v.z, b1v.w};
    unsigned short uc[8] = {c0.x, c0.y, c0.z, c0.w, c1.x, c1.y, c1.z, c1.w};
    unsigned short ud[8] = {d0.x, d0.y, d0.z, d0.w, d1.x, d1.y, d1.z, d1.w};
    unsigned short ro[8];
#pragma unroll
    for (int e = 0; e < 8; ++e) {
        float v = w00 * us2f(ua[e]) + w01 * us2f(ub[e]) + w10 * us2f(uc[e]) + w11 * us2f(ud[e]);
        bf16 r = f2b(v);
        ro[e] = *(unsigned short*)&r;
    }
    unsigned short* outp = (unsigned short*)f2w + ((size_t)z * 3072 + p) * 64 + g * 8;
    *(ushort4*)outp = (ushort4){ro[0], ro[1], ro[2], ro[3]};
    *(ushort4*)(outp + 4) = (ushort4){ro[4], ro[5], ro[6], ro[7]};
}

// ---------------------------------------------------------------------------
// 512-thread MFMA conv, 2 images/block. waves: (wz, wy, wx).
// A staged in LDS (uint4); B frag-order global with double-buffered prefetch.
// BMODE: 0 bias fp32[OCTOT]; 1 base NHWC bf16 (2,48,64,96), b=(bd0+z)/49.
// OMODE: 0 NHWC bf16+ReLU (transposed); 1 parity-pack (transposed);
//        4 NHWC bf16 NO ReLU (transposed).
// ---------------------------------------------------------------------------
template <int IC, int OCTOT, int OC_BLK, int H, int W, int MROWS, int NTAPS, int DXW,
          int DYLO, int DXLO, int BMODE, int OMODE>
__global__ __launch_bounds__(512, 4) void conv_ldz(const bf16* __restrict__ in_,
                                                   const bf16* __restrict__ wsw_,
                                                   const float* __restrict__ bias,
                                                   const bf16* __restrict__ base_,
                                                   bf16* __restrict__ out, int bd0, int cnt) {
    constexpr int NCH = IC / 32;
    constexpr int NfT = OC_BLK / 32;
    constexpr int TPXH = MROWS * W / 2;
    constexpr int MF = TPXH / 16;
    constexpr int NDY = NTAPS / DXW;
    constexpr int ROWS_IN = MROWS + NDY - 1;
    constexpr int COLS_IN = W + DXW - 1;
    constexpr int NOCF = OCTOT / 16;
    constexpr int PITCH = 40;
    constexpr int SZA = ROWS_IN * COLS_IN * PITCH;
    constexpr int OUTSH = MROWS * W * OC_BLK;
    constexpr int SMEM = (2 * SZA > OUTSH) ? 2 * SZA : OUTSH;
    __shared__ __align__(16) unsigned short s_mem[SMEM];

    const unsigned short* in = (const unsigned short*)in_;
    const unsigned short* wsw = (const unsigned short*)wsw_;
    const unsigned short* baseh = (const unsigned short*)base_;
    const int tid = threadIdx.x;
    const int wave = tid >> 6, lane = tid & 63;
    const int m = lane & 15, q = lane >> 4;
    const int wz = wave >> 2, wy = (wave >> 1) & 1, wx = wave & 1;
    const int bx = blockIdx.x, by = blockIdx.y;
    const int z0 = blockIdx.z * 2;
    const int zw = z0 + wz;
    const bool zok = zw < cnt;
    const int foff = m * PITCH + q * 8;
    const int ocbase = by * OC_BLK;

    f32x4 acc[MF][NfT];
#pragma unroll
    for (int a = 0; a < MF; ++a)
#pragma unroll
        for (int nf = 0; nf < NfT; ++nf) acc[a][nf] = (f32x4){0.f, 0.f, 0.f, 0.f};

    for (int cc = 0; cc < NCH; ++cc) {
        constexpr int SZE = ROWS_IN * COLS_IN * 4;  // uint4 units per z
        for (int i = tid; i < 2 * SZE; i += 512) {
            int zz = i / SZE;
            int r2 = i % SZE;
            int e = r2 & 3;
            int pix = r2 >> 2;
            int cI = pix % COLS_IN;
            int rr = pix / COLS_IN;
            int gy = bx * MROWS + rr + DYLO;
            int gx = cI + DXLO;
            uint4 v = {0u, 0u, 0u, 0u};
            if ((z0 + zz) < cnt && gy >= 0 && gy < H && gx >= 0 && gx < W)
                v = *(const uint4*)(in +
                                    ((size_t)((z0 + zz) * H + gy) * W + gx) * IC + cc * 32 + e * 8);
            *(uint4*)(&s_mem[zz * SZA + pix * PITCH + e * 8]) = v;
        }
        __syncthreads();
        if (zok) {
            bf16x8 bcur[NfT], bnxt[NfT];
#pragma unroll
            for (int nf = 0; nf < NfT; ++nf) {
                const int fragoc = (ocbase >> 4) + wx * NfT + nf;
                bcur[nf] = *(const bf16x8*)(wsw + (((size_t)0 * NOCF + fragoc) * NCH + cc) * 512 +
                                            lane * 8);
            }
#pragma unroll
            for (int t = 0; t < NTAPS; ++t) {
                if (t + 1 < NTAPS) {
#pragma unroll
                    for (int nf = 0; nf < NfT; ++nf) {
                        const int fragoc = (ocbase >> 4) + wx * NfT + nf;
                        bnxt[nf] = *(const bf16x8*)(wsw +
                                                    (((size_t)(t + 1) * NOCF + fragoc) * NCH + cc) *
                                                        512 +
                                                    lane * 8);
                    }
                }
                bf16x8 af[MF];
#pragma unroll
                for (int mf = 0; mf < MF; ++mf) {
                    const int pxb = wy * TPXH + mf * 16;
                    const int yl = pxb / W, xb = pxb % W;
                    const unsigned short* pa =
                        &s_mem[wz * SZA + ((yl + t / DXW) * COLS_IN + xb + t % DXW) * PITCH] + foff;
                    af[mf] = *(const bf16x8*)pa;
                }
#pragma unroll
                for (int mf = 0; mf < MF; ++mf)
#pragma unroll
                    for (int nf = 0; nf < NfT; ++nf)
                        acc[mf][nf] = __builtin_amdgcn_mfma_f32_16x16x32_bf16(af[mf], bcur[nf],
                                                                              acc[mf][nf], 0, 0, 0);
                if (t + 1 < NTAPS) {
#pragma unroll
                    for (int nf = 0; nf < NfT; ++nf) bcur[nf] = bnxt[nf];
                }
            }
        }
        __syncthreads();
    }

    // transposed coalesced epilogue
    const int bimg = (bd0 + zw) / 49;
    float bb[NfT];
    if constexpr (BMODE == 0) {
#pragma unroll
        for (int nf = 0; nf < NfT; ++nf) bb[nf] = bias[ocbase + wx * (OC_BLK / 2) + nf * 16 + m];
    }
    for (int zz = 0; zz < 2; ++zz) {
        if (wz == zz && zok) {
#pragma unroll
            for (int mf = 0; mf < MF; ++mf) {
                const int pxb = wy * TPXH + mf * 16;
#pragma unroll
                for (int r = 0; r < 4; ++r) {
                    const int px = pxb + q * 4 + r;
                    const int yl = px / W, xl = px % W;
                    const int gy = bx * MROWS + yl;
#pragma unroll
                    for (int nf = 0; nf < NfT; ++nf) {
                        const int oc = wx * (OC_BLK / 2) + nf * 16 + m;
                        float v = acc[mf][nf][r];
                        if constexpr (BMODE == 1)
                            v += us2f(baseh[(((size_t)bimg * 48 + gy) * 64 + xl) * 96 + ocbase + oc]);
                        else
                            v += bb[nf];
                        if constexpr (OMODE != 4) v = fmaxf(v, 0.f);
                        bf16 bv = f2b(v);
                        s_mem[px * OC_BLK + oc] = *(unsigned short*)&bv;
                    }
                }
            }
        }
        __syncthreads();
        const int z = z0 + zz;
        if (z < cnt) {
            constexpr int TOT16 = MROWS * W * OC_BLK / 8;
            for (int g = tid; g < TOT16; g += 512) {
                const int o = g * 8;
                if constexpr (OMODE == 1) {
                    // parity pack: MROWS==2, W==64, OC_BLK==96
                    const int xx = o / 384;
                    const int rr = o % 384;
                    const int pp = rr / 96;
                    const int oco = rr % 96;
                    const int px = (pp >> 1) * 64 + 2 * xx + (pp & 1);
                    uint4 vv = *(const uint4*)&s_mem[px * 96 + oco];
                    *(uint4*)((unsigned short*)out + (((size_t)z * 24 + bx) * 32 + xx) * 384 + rr) =
                        vv;
                } else {
                    uint4 vv = *(const uint4*)&s_mem[o];
                    const int px = o / OC_BLK;
                    const int oco = o % OC_BLK;
                    const int gy = bx * MROWS + px / W;
                    const int xl = px % W;
                    if constexpr (OMODE == 4)
                        *(uint4*)((unsigned short*)out +
                                  (((size_t)z * H + gy) * W + xl) * OCTOT + ocbase + oco) = vv;
                    else
                        *(uint4*)((unsigned short*)out +
                                  (((size_t)z * H + gy) * W + xl) * OCTOT + ocbase + oco) = vv;
                }
            }
        }
        __syncthreads();
    }
}

// ---------------------------------------------------------------------------
// Merged 4-class deconv: x3 (cnt,24,32,64) -> xd (cnt,48,64,32), ReLU.
// 8 waves: (wz, class). Each wave: full 128-px tile (MF=8), its class's 4 taps.
// ---------------------------------------------------------------------------
__global__ __launch_bounds__(512, 4) void deconv_k4(const bf16* __restrict__ in_,
                                                    const bf16* __restrict__ wswd_,
                                                    const float* __restrict__ bias,
                                                    bf16* __restrict__ out, int cnt) {
    constexpr int PITCH = 40;
    constexpr int SZA = 6 * 34 * PITCH;  // 8160 shorts per (z,cc)
    __shared__ __align__(16) unsigned short s_mem[16384];  // max(2*SZA, 8*64*32)

    const unsigned short* in = (const unsigned short*)in_;
    const unsigned short* wsw = (const unsigned short*)wswd_;
    const int tid = threadIdx.x;
    const int wave = tid >> 6, lane = tid & 63;
    const int m = lane & 15, q = lane >> 4;
    const int wz = wave >> 2, cls = wave & 3;
    const int qy = cls >> 1, qx = cls & 1;
    const int bx = blockIdx.x;
    const int z0 = blockIdx.z * 2;
    const int zw = z0 + wz;
    const bool zok = zw < cnt;
    const int foff = m * PITCH + q * 8;

    f32x4 acc[8][2];
#pragma unroll
    for (int a = 0; a < 8; ++a) {
        acc[a][0] = (f32x4){0.f, 0.f, 0.f, 0.f};
        acc[a][1] = (f32x4){0.f, 0.f, 0.f, 0.f};
    }

    for (int cc = 0; cc < 2; ++cc) {
        constexpr int SZE = 6 * 34 * 4;  // uint4 units per z
        for (int i = tid; i < 2 * SZE; i += 512) {
            int zz = i / SZE;
            int r2 = i % SZE;
            int e = r2 & 3;
            int pix = r2 >> 2;
            int cI = pix % 34;
            int rr = pix / 34;
            int gy = bx * 4 + rr - 1;
            int gx = cI - 1;
            uint4 v = {0u, 0u, 0u, 0u};
            if ((z0 + zz) < cnt && gy >= 0 && gy < 24 && gx >= 0 && gx < 32)
                v = *(const uint4*)(in + ((size_t)((z0 + zz) * 24 + gy) * 32 + gx) * 64 + cc * 32 +
                                    e * 8);
            *(uint4*)(&s_mem[zz * SZA + pix * PITCH + e * 8]) = v;
        }
        __syncthreads();
        if (zok) {
            bf16x8 bcur[2], bnxt[2];
#pragma unroll
            for (int nf = 0; nf < 2; ++nf)
                bcur[nf] = *(const bf16x8*)(wsw + cls * 8192 + 0 * 2048 + nf * 1024 + cc * 512 +
                                            lane * 8);
#pragma unroll
            for (int t = 0; t < 4; ++t) {
                if (t + 1 < 4) {
#pragma unroll
                    for (int nf = 0; nf < 2; ++nf)
                        bnxt[nf] = *(const bf16x8*)(wsw + cls * 8192 + (t + 1) * 2048 + nf * 1024 +
                                                    cc * 512 + lane * 8);
                }
                const int dy = qy - 1 + (t >> 1);
                const int dx = qx - 1 + (t & 1);
                bf16x8 af[8];
#pragma unroll
                for (int mf = 0; mf < 8; ++mf) {
                    const int yl = mf >> 1, xb = (mf & 1) * 16;
                    const unsigned short* pa =
                        &s_mem[wz * SZA + ((yl + dy + 1) * 34 + xb + dx + 1) * PITCH] + foff;
                    af[mf] = *(const bf16x8*)pa;
                }
#pragma unroll
                for (int mf = 0; mf < 8; ++mf)
#pragma unroll
                    for (int nf = 0; nf < 2; ++nf)
                        acc[mf][nf] = __builtin_amdgcn_mfma_f32_16x16x32_bf16(af[mf], bcur[nf],
                                                                              acc[mf][nf], 0, 0, 0);
                if (t + 1 < 4) {
                    bcur[0] = bnxt[0];
                    bcur[1] = bnxt[1];
                }
            }
        }
        __syncthreads();
    }

    const float bb0 = bias[m], bb1 = bias[16 + m];
    for (int zz = 0; zz < 2; ++zz) {
        if (wz == zz && zok) {
#pragma unroll
            for (int mf = 0; mf < 8; ++mf) {
#pragma unroll
                for (int r = 0; r < 4; ++r) {
                    const int px = mf * 16 + q * 4 + r;
                    const int yl = px >> 5, xl = px & 31;
                    const int opx = (2 * yl + qy) * 64 + 2 * xl + qx;
                    float v0 = fmaxf(acc[mf][0][r] + bb0, 0.f);
                    float v1 = fmaxf(acc[mf][1][r] + bb1, 0.f);
                    bf16 b0 = f2b(v0), b1 = f2b(v1);
                    s_mem[opx * 32 + m] = *(unsigned short*)&b0;
                    s_mem[opx * 32 + 16 + m] = *(unsigned short*)&b1;
                }
            }
        }
        __syncthreads();
        const int z = z0 + zz;
        if (z < cnt) {
            for (int g = tid; g < 2048; g += 512) {
                const int o = g * 8;
                *(uint4*)((unsigned short*)out + ((size_t)z * 3072 + bx * 512) * 32 + o) =
                    *(const uint4*)&s_mem[o];
            }
        }
        __syncthreads();
    }
}

// ---------------------------------------------------------------------------
// conv5: 3x3, 32->1, no ReLU. in NHWC bf16 (cnt,48,64,32) -> cost fp32
// ---------------------------------------------------------------------------
__global__ __launch_bounds__(256) void conv5_k(const bf16* __restrict__ in_,
                                               const float* __restrict__ w5,
                                               const float* __restrict__ b5,
                                               float* __restrict__ cost, int bd0, int cnt) {
    __shared__ float s_w5[9][32];
    const int tid = threadIdx.x;
    for (int i = tid; i < 288; i += 256) {
        int ic = i % 32, t = i / 32;
        s_w5[t][ic] = w5[ic * 9 + t];
    }
    __syncthreads();
    int idx = blockIdx.x * 256 + tid;
    if (idx >= cnt * 3072) return;
    int p = idx % 3072, z = idx / 3072;
    int y = p >> 6, x = p & 63;
    const unsigned short* in = (const unsigned short*)in_;
    float acc = b5[0];
#pragma unroll
    for (int ky = 0; ky < 3; ++ky) {
        int gy = y + ky - 1;
        if (gy < 0 || gy >= 48) continue;
#pragma unroll
        for (int kx = 0; kx < 3; ++kx) {
            int gx = x + kx - 1;
            if (gx < 0 || gx >= 64) continue;
            const ushort4* src = (const ushort4*)(in + ((size_t)(z * 48 + gy) * 64 + gx) * 32);
            const float* wr = s_w5[ky * 3 + kx];
#pragma unroll
            for (int e = 0; e < 8; ++e) {
                ushort4 u = src[e];
                acc = fmaf(us2f(u.x), wr[e * 4 + 0], acc);
                acc = fmaf(us2f(u.y), wr[e * 4 + 1], acc);
                acc = fmaf(us2f(u.z), wr[e * 4 + 2], acc);
                acc = fmaf(us2f(u.w), wr[e * 4 + 3], acc);
            }
        }
    }
    cost[(size_t)(bd0 + z) * 3072 + p] = acc;
}

// ---------------------------------------------------------------------------
// DAP (49x49) + softmax + flow expectation + coords. out fp32 (2,2,48,64)
// ---------------------------------------------------------------------------
__global__ __launch_bounds__(256) void dap_flow(const float* __restrict__ cost,
                                                const float* __restrict__ wdap,
                                                const float* __restrict__ coords,
                                                float* __restrict__ outp) {
    __shared__ float s_w[49 * 49];
    int tid = threadIdx.x;
    for (int i = tid; i < 2401; i += 256) s_w[i] = wdap[i];
    __syncthreads();
    int idx = blockIdx.x * 256 + tid;
    if (idx >= 2 * 3072) return;
    int p = idx % 3072, b = idx / 3072;
    float c[49];
#pragma unroll
    for (int d = 0; d < 49; ++d) c[d] = cost[((size_t)(b * 49 + d)) * 3072 + p];
    float mx = -1e30f;
    for (int e = 0; e < 49; ++e) {
        float s = 0.f;
#pragma unroll
        for (int d = 0; d < 49; ++d) s = fmaf(s_w[e * 49 + d], c[d], s);
        mx = fmaxf(mx, s);
    }
    float sum = 0.f, sx = 0.f, sy = 0.f;
    for (int e = 0; e < 49; ++e) {
        float s = 0.f;
#pragma unroll
        for (int d = 0; d < 49; ++d) s = fmaf(s_w[e * 49 + d], c[d], s);
        float pr = __expf(s - mx);
        sum += pr;
        sx += pr * (float)(e % 7 - 3);
        sy += pr * (float)(e / 7 - 3);
    }
    float inv = 1.f / sum;
    outp[(size_t)(b * 2 + 0) * 3072 + p] = coords[(size_t)(b * 2 + 0) * 3072 + p] + sx * inv;
    outp[(size_t)(b * 2 + 1) * 3072 + p] = coords[(size_t)(b * 2 + 1) * 3072 + p] + sy * inv;
}

// ---------------------------------------------------------------------------
extern "C" void kernel_launch(void* const* d_in, const int* in_sizes, int n_in,
                              void* d_out, int out_size, void* d_ws, size_t ws_size,
                              hipStream_t stream) {
    (void)in_sizes; (void)n_in;
    const float* feat1 = (const float*)d_in[0];
    const float* feat2 = (const float*)d_in[1];
    const float* coords = (const float*)d_in[2];
    const float* w0 = (const float*)d_in[3];
    const float* b0 = (const float*)d_in[4];
    const float* w1 = (const float*)d_in[5];
    const float* b1 = (const float*)d_in[6];
    const float* w2 = (const float*)d_in[7];
    const float* b2 = (const float*)d_in[8];
    const float* w3 = (const float*)d_in[9];
    const float* b3 = (const float*)d_in[10];
    const float* wd = (const float*)d_in[11];
    const float* bdc = (const float*)d_in[12];
    const float* w5 = (const float*)d_in[13];
    const float* b5 = (const float*)d_in[14];
    const float* wdap = (const float*)d_in[15];
    float* outp = (float*)d_out;

    // workspace (fixed):
    //  wsw0 @0 (110592) | wsw0a @110592 (110592) | wsw1 @221184 (393216)
    //  wsw2 @614400 (294912) | wsw3 @909312 (147456) | wswd @1056768 (65536)
    //  f1n @1122304 (786432) | part0(bf16) @1908736 (1179648) | cost @3088384 (1204224)
    //  f2n @4292608 (786432) | fixed_end = 5079040
    char* ws = (char*)d_ws;
    bf16* wsw0 = (bf16*)(ws + 0);
    bf16* wsw0a = (bf16*)(ws + 110592);
    bf16* wsw1 = (bf16*)(ws + 221184);
    bf16* wsw2 = (bf16*)(ws + 614400);
    bf16* wsw3 = (bf16*)(ws + 909312);
    bf16* wswd = (bf16*)(ws + 1056768);
    bf16* f1n = (bf16*)(ws + 1122304);
    bf16* part0 = (bf16*)(ws + 1908736);
    float* cost = (float*)(ws + 3088384);
    bf16* f2n = (bf16*)(ws + 4292608);
    const size_t fixed_end = 5079040;

    const int cand[7] = {98, 49, 25, 14, 7, 2, 1};
    int nb = 0;
    for (int i = 0; i < 7; ++i) {
        if (fixed_end + (size_t)983040 * cand[i] <= ws_size) { nb = cand[i]; break; }
    }
    if (nb == 0) {
        float val = 10000.f + (float)(ws_size >> 20);
        sentinel_k<<<dim3((out_size + 255) / 256), 256, 0, stream>>>(outp, out_size, val);
        return;
    }
    char* regA = ws + fixed_end;
    char* regB = regA + (size_t)393216 * nb;
    bf16* f2w = (bf16*)regA;  // (nb,48,64,64)
    bf16* x1 = (bf16*)regA;   // (nb,24,32,128)
    bf16* x3 = (bf16*)regA;   // (nb,24,32,64)
    bf16* x0p = (bf16*)regB;  // (nb,24,32,384) parity-packed
    bf16* x2 = (bf16*)regB;   // (nb,24,32,128)
    bf16* xd = (bf16*)regB;   // (nb,48,64,32)

    // prologue: 2 launches + part0
    pack_all<<<dim3(2192), 256, 0, stream>>>(w0, w1, w2, w3, wd, wsw0, wsw0a, wsw1, wsw2, wsw3,
                                             wswd);
    to_nhwc2<<<dim3(3072), 256, 0, stream>>>(feat1, feat2, f1n, f2n);
    // part0 = conv3x3(f1n, w0[:,:64]) + b0 -> bf16 NHWC (2,48,64,96), no ReLU
    conv_ldz<64, 96, 96, 48, 64, 2, 9, 3, -1, -1, 0, 4>
        <<<dim3(24, 1, 1), 512, 0, stream>>>(f1n, wsw0a, b0, nullptr, part0, 0, 2);

    for (int s = 0; s < 98; s += nb) {
        int cnt = (98 - s < nb) ? (98 - s) : nb;
        int zp = (cnt + 1) / 2;
        warp_kernel<<<dim3(cnt * 96), 256, 0, stream>>>(f2n, coords, f2w, s, cnt);
        // conv0: IC=64 taps3x3 OC=96, base=part0(bf16), parity-pack out
        conv_ldz<64, 96, 96, 48, 64, 2, 9, 3, -1, -1, 1, 1>
            <<<dim3(24, 1, zp), 512, 0, stream>>>(f2w, wsw0, nullptr, part0, x0p, s, cnt);
        // conv1: IC=384 taps{-1,0}^2 OC=128, 128px tile, oc split 2
        conv_ldz<384, 128, 64, 24, 32, 4, 4, 2, -1, -1, 0, 0>
            <<<dim3(6, 2, zp), 512, 0, stream>>>(x0p, wsw1, b1, nullptr, x1, s, cnt);
        // conv2: IC=128 taps3x3 OC=128, 128px tile, oc split 2
        conv_ldz<128, 128, 64, 24, 32, 4, 9, 3, -1, -1, 0, 0>
            <<<dim3(6, 2, zp), 512, 0, stream>>>(x1, wsw2, b2, nullptr, x2, s, cnt);
        // conv3: IC=128 taps3x3 OC=64, 128px tile, oc split 2
        conv_ldz<128, 64, 32, 24, 32, 4, 9, 3, -1, -1, 0, 0>
            <<<dim3(6, 2, zp), 512, 0, stream>>>(x2, wsw3, b3, nullptr, x3, s, cnt);
        // deconv: merged 4 classes, x3 staged once
        deconv_k4<<<dim3(6, 1, zp), 512, 0, stream>>>(x3, wswd, bdc, xd, cnt);
        // conv5
        conv5_k<<<dim3(cnt * 12), 256, 0, stream>>>(xd, w5, b5, cost, s, cnt);
    }

    dap_flow<<<dim3(24), 256, 0, stream>>>(cost, wdap, coords, outp);
}

// Round 11
// 369.683 us; speedup vs baseline: 2.0995x; 1.0545x over previous
//
#include <hip/hip_runtime.h>
#include <hip/hip_bf16.h>

using bf16 = __hip_bfloat16;
typedef __attribute__((ext_vector_type(8))) __bf16 bf16x8;
typedef __attribute__((ext_vector_type(4))) float f32x4;

static __device__ __forceinline__ bf16 f2b(float v) { return __float2bfloat16(v); }
static __device__ __forceinline__ float us2f(unsigned short u) {
    return __uint_as_float(((unsigned)u) << 16);
}

// Problem: B=2, C=64, H=48, W=64, D=49, BD=98. fp32 I/O.
// MFMA pipeline, NHWC bf16. 256-thr blocks, 1 image/block, waves split PIXELS
// 4-way (each wave computes ALL oc frags -> A ds_read per MFMA halved).
// B pre-swizzled frag-order global, double-buffered prefetch.

// ---------------------------------------------------------------------------
__global__ void sentinel_k(float* __restrict__ out, int nel, float val) {
    int i = blockIdx.x * 256 + threadIdx.x;
    if (i < nel) out[i] = val;
}

// ---------------------------------------------------------------------------
// All weight packs in ONE launch. Frag-order layout:
// o = (((t*NOCF + ocf)*NCH + cc)*64 + lane)*8 + j ; lane=q*16+m
// elem j = W[k=cc*32+q*8+j][oc=ocf*16+m] at tap t.
// ---------------------------------------------------------------------------
__global__ void pack_all(const float* __restrict__ w0, const float* __restrict__ w1,
                         const float* __restrict__ w2, const float* __restrict__ w3,
                         const float* __restrict__ wd, bf16* __restrict__ wsw0,
                         bf16* __restrict__ wsw0a, bf16* __restrict__ wsw1,
                         bf16* __restrict__ wsw2, bf16* __restrict__ wsw3,
                         bf16* __restrict__ wswd) {
    int i = blockIdx.x * 256 + threadIdx.x;
    if (i < 110592) {
        int icbase = (i < 55296) ? 64 : 0;
        bf16* dst = (i < 55296) ? wsw0 : wsw0a;
        int o = (i < 55296) ? i : i - 55296;
        int j = o & 7, lane = (o >> 3) & 63;
        int m = lane & 15, q = lane >> 4;
        int cc = (o >> 9) & 1;
        int fragid = o >> 10;
        int t = fragid / 6, ocf = fragid % 6;
        int oc = ocf * 16 + m, ic = cc * 32 + q * 8 + j;
        dst[o] = f2b(w0[((size_t)oc * 128 + icbase + ic) * 9 + t]);
    } else if (i < 307200) {
        int o = i - 110592;
        int j = o & 7, lane = (o >> 3) & 63;
        int m = lane & 15, q = lane >> 4;
        int cc = (o >> 9) % 12;
        int fragid = (o >> 9) / 12;
        int t2 = fragid / 8, ocf = fragid % 8;
        int oc = ocf * 16 + m;
        int pc = cc * 32 + q * 8 + j;
        int dy = (t2 < 2) ? -1 : 0;
        int dx = (t2 & 1) ? 0 : -1;
        int p = pc / 96, ic = pc % 96;
        int py = p >> 1, px = p & 1;
        int ky = (dy == -1) ? (py == 1 ? 0 : -1) : (py == 0 ? 1 : 2);
        int kx = (dx == -1) ? (px == 1 ? 0 : -1) : (px == 0 ? 1 : 2);
        float v = (ky >= 0 && kx >= 0) ? w1[((size_t)oc * 96 + ic) * 9 + ky * 3 + kx] : 0.f;
        wsw1[o] = f2b(v);
    } else if (i < 454656) {
        int o = i - 307200;
        int j = o & 7, lane = (o >> 3) & 63;
        int m = lane & 15, q = lane >> 4;
        int cc = (o >> 9) % 4;
        int fragid = (o >> 9) / 4;
        int t = fragid / 8, ocf = fragid % 8;
        int oc = ocf * 16 + m, ic = cc * 32 + q * 8 + j;
        wsw2[o] = f2b(w2[((size_t)oc * 128 + ic) * 9 + t]);
    } else if (i < 528384) {
        int o = i - 454656;
        int j = o & 7, lane = (o >> 3) & 63;
        int m = lane & 15, q = lane >> 4;
        int cc = (o >> 9) % 4;
        int fragid = (o >> 9) / 4;
        int t = fragid / 4, ocf = fragid % 4;
        int oc = ocf * 16 + m, ic = cc * 32 + q * 8 + j;
        wsw3[o] = f2b(w3[((size_t)oc * 128 + ic) * 9 + t]);
    } else if (i < 561152) {
        int o = i - 528384;
        int j = o & 7, lane = (o >> 3) & 63;
        int m = lane & 15, q = lane >> 4;
        int cc = (o >> 9) & 1;
        int ocf = (o >> 10) & 1;
        int t2 = (o >> 11) & 3;
        int c = o >> 13;
        int oc = ocf * 16 + m, ic = cc * 32 + q * 8 + j;
        int qy = c >> 1, qx = c & 1;
        int dy = qy - 1 + (t2 >> 1), dx = qx - 1 + (t2 & 1);
        int ky = (qy == 0) ? (dy == -1 ? 0 : 2) : (dy == 0 ? 1 : 3);
        int kx = (qx == 0) ? (dx == -1 ? 0 : 2) : (dx == 0 ? 1 : 3);
        wswd[o] = f2b(wd[((size_t)oc * 64 + ic) * 16 + ky * 4 + kx]);
    }
}

// ---------------------------------------------------------------------------
// feat1+feat2 NCHW fp32 -> NHWC bf16, one launch
// ---------------------------------------------------------------------------
__global__ void to_nhwc2(const float* __restrict__ feat1, const float* __restrict__ feat2,
                         bf16* __restrict__ f1n, bf16* __restrict__ f2n) {
    int i = blockIdx.x * 256 + threadIdx.x;
    const float* src = (i < 393216) ? feat1 : feat2;
    bf16* dst = (i < 393216) ? f1n : f2n;
    int o = (i < 393216) ? i : i - 393216;
    if (o >= 393216) return;
    int c = o & 63;
    int p = (o >> 6) % 3072;
    int b = o / (3072 * 64);
    dst[o] = f2b(src[((size_t)b * 64 + c) * 3072 + p]);
}

// ---------------------------------------------------------------------------
// warp: bilinear from f2n (NHWC bf16). thread = (pixel, 8-channel group), 16B.
// ---------------------------------------------------------------------------
__global__ __launch_bounds__(256) void warp_kernel(const bf16* __restrict__ f2n,
                                                   const float* __restrict__ coords,
                                                   bf16* __restrict__ f2w, int bd0, int cnt) {
    int idx = blockIdx.x * 256 + threadIdx.x;
    if (idx >= cnt * 3072 * 8) return;
    int g = idx & 7;
    int pix = idx >> 3;
    int p = pix % 3072;
    int z = pix / 3072;
    int bd = bd0 + z;
    int b = bd / 49, d = bd % 49;
    float du = (float)(d % 7 - 3), dv = (float)(d / 7 - 3);
    float cx = coords[(size_t)(b * 2 + 0) * 3072 + p] + du;
    float cy = coords[(size_t)(b * 2 + 1) * 3072 + p] + dv;
    float x0f = floorf(cx), y0f = floorf(cy);
    float wx = cx - x0f, wy = cy - y0f;
    int x0 = (int)x0f, y0 = (int)y0f;
    int x1 = x0 + 1, y1 = y0 + 1;
    bool vx0 = (x0 >= 0) && (x0 < 64), vx1 = (x1 >= 0) && (x1 < 64);
    bool vy0 = (y0 >= 0) && (y0 < 48), vy1 = (y1 >= 0) && (y1 < 48);
    int xc0 = min(max(x0, 0), 63), xc1 = min(max(x1, 0), 63);
    int yc0 = min(max(y0, 0), 47), yc1 = min(max(y1, 0), 47);
    float w00 = (vx0 && vy0) ? (1.f - wx) * (1.f - wy) : 0.f;
    float w01 = (vx1 && vy0) ? wx * (1.f - wy) : 0.f;
    float w10 = (vx0 && vy1) ? (1.f - wx) * wy : 0.f;
    float w11 = (vx1 && vy1) ? wx * wy : 0.f;
    const unsigned short* f2 = (const unsigned short*)f2n + (size_t)b * 3072 * 64 + g * 8;
    ushort4 a0 = *(const ushort4*)(f2 + (size_t)(yc0 * 64 + xc0) * 64);
    ushort4 a1 = *(const ushort4*)(f2 + (size_t)(yc0 * 64 + xc0) * 64 + 4);
    ushort4 b0v = *(const ushort4*)(f2 + (size_t)(yc0 * 64 + xc1) * 64);
    ushort4 b1v = *(const ushort4*)(f2 + (size_t)(yc0 * 64 + xc1) * 64 + 4);
    ushort4 c0 = *(const ushort4*)(f2 + (size_t)(yc1 * 64 + xc0) * 64);
    ushort4 c1 = *(const ushort4*)(f2 + (size_t)(yc1 * 64 + xc0) * 64 + 4);
    ushort4 d0 = *(const ushort4*)(f2 + (size_t)(yc1 * 64 + xc1) * 64);
    ushort4 d1 = *(const ushort4*)(f2 + (size_t)(yc1 * 64 + xc1) * 64 + 4);
    unsigned short ua[8] = {a0.x, a0.y, a0.z, a0.w, a1.x, a1.y, a1.z, a1.w};
    unsigned short ub[8] = {b0v.x, b0v.y, b0v.z, b0v.w, b1v.x, b1v.y, b1v.z, b1v.w};
    unsigned short uc[8] = {c0.x, c0.y, c0.z, c0.w, c1.x, c1.y, c1.z, c1.w};
    unsigned short ud[8] = {d0.x, d0.y, d0.z, d0.w, d1.x, d1.y, d1.z, d1.w};
    unsigned short ro[8];
#pragma unroll
    for (int e = 0; e < 8; ++e) {
        float v = w00 * us2f(ua[e]) + w01 * us2f(ub[e]) + w10 * us2f(uc[e]) + w11 * us2f(ud[e]);
        bf16 r = f2b(v);
        ro[e] = *(unsigned short*)&r;
    }
    unsigned short* outp = (unsigned short*)f2w + ((size_t)z * 3072 + p) * 64 + g * 8;
    *(ushort4*)outp = (ushort4){ro[0], ro[1], ro[2], ro[3]};
    *(ushort4*)(outp + 4) = (ushort4){ro[4], ro[5], ro[6], ro[7]};
}

// ---------------------------------------------------------------------------
// 256-thread MFMA conv, 1 image/block. Waves split PIXELS 4-way; each wave
// computes all OC_BLK frags (NfT = OC_BLK/16) -> A ds_read per MFMA halved.
// A staged in LDS (uint4); B frag-order global double-buffered.
// BMODE: 0 bias fp32[OCTOT]; 1 base NHWC bf16 (2,48,64,96), b=(bd0+z)/49.
// OMODE: 0 NHWC bf16+ReLU (transposed); 1 parity-pack (transposed);
//        4 NHWC bf16 NO ReLU (transposed).
// ---------------------------------------------------------------------------
template <int IC, int OCTOT, int OC_BLK, int H, int W, int MROWS, int NTAPS, int DXW,
          int DYLO, int DXLO, int BMODE, int OMODE>
__global__ __launch_bounds__(256, 4) void conv_px4(const bf16* __restrict__ in_,
                                                   const bf16* __restrict__ wsw_,
                                                   const float* __restrict__ bias,
                                                   const bf16* __restrict__ base_,
                                                   bf16* __restrict__ out, int bd0) {
    constexpr int NCH = IC / 32;
    constexpr int NfT = OC_BLK / 16;      // all oc frags per wave
    constexpr int TPXQ = MROWS * W / 4;   // px per wave
    constexpr int MF = TPXQ / 16;         // A frags per wave
    constexpr int NDY = NTAPS / DXW;
    constexpr int ROWS_IN = MROWS + NDY - 1;
    constexpr int COLS_IN = W + DXW - 1;
    constexpr int NOCF = OCTOT / 16;
    constexpr int PITCH = 40;
    constexpr int SZA = ROWS_IN * COLS_IN * PITCH;
    constexpr int OUTSH = MROWS * W * OC_BLK;
    constexpr int SMEM = (SZA > OUTSH) ? SZA : OUTSH;
    __shared__ __align__(16) unsigned short s_mem[SMEM];

    const unsigned short* in = (const unsigned short*)in_;
    const unsigned short* wsw = (const unsigned short*)wsw_;
    const unsigned short* baseh = (const unsigned short*)base_;
    const int tid = threadIdx.x;
    const int wp = tid >> 6, lane = tid & 63;
    const int m = lane & 15, q = lane >> 4;
    const int bx = blockIdx.x, by = blockIdx.y, z = blockIdx.z;
    const int foff = m * PITCH + q * 8;
    const int ocbase = by * OC_BLK;

    f32x4 acc[MF][NfT];
#pragma unroll
    for (int a = 0; a < MF; ++a)
#pragma unroll
        for (int nf = 0; nf < NfT; ++nf) acc[a][nf] = (f32x4){0.f, 0.f, 0.f, 0.f};

    for (int cc = 0; cc < NCH; ++cc) {
        constexpr int SZE = ROWS_IN * COLS_IN * 4;  // uint4 units
        for (int i = tid; i < SZE; i += 256) {
            int e = i & 3;
            int pix = i >> 2;
            int cI = pix % COLS_IN;
            int rr = pix / COLS_IN;
            int gy = bx * MROWS + rr + DYLO;
            int gx = cI + DXLO;
            uint4 v = {0u, 0u, 0u, 0u};
            if (gy >= 0 && gy < H && gx >= 0 && gx < W)
                v = *(const uint4*)(in + ((size_t)(z * H + gy) * W + gx) * IC + cc * 32 + e * 8);
            *(uint4*)(&s_mem[pix * PITCH + e * 8]) = v;
        }
        __syncthreads();
        {
            bf16x8 bcur[NfT], bnxt[NfT];
#pragma unroll
            for (int nf = 0; nf < NfT; ++nf) {
                const int fragoc = (ocbase >> 4) + nf;
                bcur[nf] = *(const bf16x8*)(wsw + (((size_t)0 * NOCF + fragoc) * NCH + cc) * 512 +
                                            lane * 8);
            }
#pragma unroll
            for (int t = 0; t < NTAPS; ++t) {
                if (t + 1 < NTAPS) {
#pragma unroll
                    for (int nf = 0; nf < NfT; ++nf) {
                        const int fragoc = (ocbase >> 4) + nf;
                        bnxt[nf] = *(const bf16x8*)(wsw +
                                                    (((size_t)(t + 1) * NOCF + fragoc) * NCH + cc) *
                                                        512 +
                                                    lane * 8);
                    }
                }
                bf16x8 af[MF];
#pragma unroll
                for (int mf = 0; mf < MF; ++mf) {
                    const int pxb = wp * TPXQ + mf * 16;
                    const int yl = pxb / W, xb = pxb % W;
                    const unsigned short* pa =
                        &s_mem[((yl + t / DXW) * COLS_IN + xb + t % DXW) * PITCH] + foff;
                    af[mf] = *(const bf16x8*)pa;
                }
#pragma unroll
                for (int mf = 0; mf < MF; ++mf)
#pragma unroll
                    for (int nf = 0; nf < NfT; ++nf)
                        acc[mf][nf] = __builtin_amdgcn_mfma_f32_16x16x32_bf16(af[mf], bcur[nf],
                                                                              acc[mf][nf], 0, 0, 0);
                if (t + 1 < NTAPS) {
#pragma unroll
                    for (int nf = 0; nf < NfT; ++nf) bcur[nf] = bnxt[nf];
                }
            }
        }
        __syncthreads();
    }

    // transposed coalesced epilogue (all waves write disjoint px ranges)
    const int bimg = (bd0 + z) / 49;
    float bb[NfT];
    if constexpr (BMODE == 0) {
#pragma unroll
        for (int nf = 0; nf < NfT; ++nf) bb[nf] = bias[ocbase + nf * 16 + m];
    }
#pragma unroll
    for (int mf = 0; mf < MF; ++mf) {
        const int pxb = wp * TPXQ + mf * 16;
#pragma unroll
        for (int r = 0; r < 4; ++r) {
            const int px = pxb + q * 4 + r;
            const int yl = px / W, xl = px % W;
            const int gy = bx * MROWS + yl;
#pragma unroll
            for (int nf = 0; nf < NfT; ++nf) {
                const int oc = nf * 16 + m;
                float v = acc[mf][nf][r];
                if constexpr (BMODE == 1)
                    v += us2f(baseh[(((size_t)bimg * 48 + gy) * 64 + xl) * 96 + ocbase + oc]);
                else
                    v += bb[nf];
                if constexpr (OMODE != 4) v = fmaxf(v, 0.f);
                bf16 bv = f2b(v);
                s_mem[px * OC_BLK + oc] = *(unsigned short*)&bv;
            }
        }
    }
    __syncthreads();
    constexpr int TOT16 = MROWS * W * OC_BLK / 8;
    for (int g = tid; g < TOT16; g += 256) {
        const int o = g * 8;
        if constexpr (OMODE == 1) {
            // parity pack: MROWS==2, W==64, OC_BLK==96
            const int xx = o / 384;
            const int rr = o % 384;
            const int pp = rr / 96;
            const int oco = rr % 96;
            const int px = (pp >> 1) * 64 + 2 * xx + (pp & 1);
            uint4 vv = *(const uint4*)&s_mem[px * 96 + oco];
            *(uint4*)((unsigned short*)out + (((size_t)z * 24 + bx) * 32 + xx) * 384 + rr) = vv;
        } else {
            uint4 vv = *(const uint4*)&s_mem[o];
            const int px = o / OC_BLK;
            const int oco = o % OC_BLK;
            const int gy = bx * MROWS + px / W;
            const int xl = px % W;
            *(uint4*)((unsigned short*)out + (((size_t)z * H + gy) * W + xl) * OCTOT + ocbase +
                      oco) = vv;
        }
    }
}

// ---------------------------------------------------------------------------
// Merged 4-class deconv, 256 thr, 1 image/block. wave = parity class.
// x3 (cnt,24,32,64) -> xd (cnt,48,64,32), ReLU.
// ---------------------------------------------------------------------------
__global__ __launch_bounds__(256, 4) void deconv_c4(const bf16* __restrict__ in_,
                                                    const bf16* __restrict__ wswd_,
                                                    const float* __restrict__ bias,
                                                    bf16* __restrict__ out) {
    constexpr int PITCH = 40;
    __shared__ __align__(16) unsigned short s_mem[16384];  // max(6*34*40, 8*64*32)

    const unsigned short* in = (const unsigned short*)in_;
    const unsigned short* wsw = (const unsigned short*)wswd_;
    const int tid = threadIdx.x;
    const int cls = tid >> 6, lane = tid & 63;
    const int m = lane & 15, q = lane >> 4;
    const int qy = cls >> 1, qx = cls & 1;
    const int bx = blockIdx.x;
    const int z = blockIdx.y;
    const int foff = m * PITCH + q * 8;

    f32x4 acc[8][2];
#pragma unroll
    for (int a = 0; a < 8; ++a) {
        acc[a][0] = (f32x4){0.f, 0.f, 0.f, 0.f};
        acc[a][1] = (f32x4){0.f, 0.f, 0.f, 0.f};
    }

    for (int cc = 0; cc < 2; ++cc) {
        constexpr int SZE = 6 * 34 * 4;
        for (int i = tid; i < SZE; i += 256) {
            int e = i & 3;
            int pix = i >> 2;
            int cI = pix % 34;
            int rr = pix / 34;
            int gy = bx * 4 + rr - 1;
            int gx = cI - 1;
            uint4 v = {0u, 0u, 0u, 0u};
            if (gy >= 0 && gy < 24 && gx >= 0 && gx < 32)
                v = *(const uint4*)(in + ((size_t)(z * 24 + gy) * 32 + gx) * 64 + cc * 32 + e * 8);
            *(uint4*)(&s_mem[pix * PITCH + e * 8]) = v;
        }
        __syncthreads();
        {
            bf16x8 bcur[2], bnxt[2];
#pragma unroll
            for (int nf = 0; nf < 2; ++nf)
                bcur[nf] = *(const bf16x8*)(wsw + cls * 8192 + nf * 1024 + cc * 512 + lane * 8);
#pragma unroll
            for (int t = 0; t < 4; ++t) {
                if (t + 1 < 4) {
#pragma unroll
                    for (int nf = 0; nf < 2; ++nf)
                        bnxt[nf] = *(const bf16x8*)(wsw + cls * 8192 + (t + 1) * 2048 + nf * 1024 +
                                                    cc * 512 + lane * 8);
                }
                const int dy = qy - 1 + (t >> 1);
                const int dx = qx - 1 + (t & 1);
                bf16x8 af[8];
#pragma unroll
                for (int mf = 0; mf < 8; ++mf) {
                    const int yl = mf >> 1, xb = (mf & 1) * 16;
                    const unsigned short* pa =
                        &s_mem[((yl + dy + 1) * 34 + xb + dx + 1) * PITCH] + foff;
                    af[mf] = *(const bf16x8*)pa;
                }
#pragma unroll
                for (int mf = 0; mf < 8; ++mf)
#pragma unroll
                    for (int nf = 0; nf < 2; ++nf)
                        acc[mf][nf] = __builtin_amdgcn_mfma_f32_16x16x32_bf16(af[mf], bcur[nf],
                                                                              acc[mf][nf], 0, 0, 0);
                if (t + 1 < 4) {
                    bcur[0] = bnxt[0];
                    bcur[1] = bnxt[1];
                }
            }
        }
        __syncthreads();
    }

    const float bb0 = bias[m], bb1 = bias[16 + m];
#pragma unroll
    for (int mf = 0; mf < 8; ++mf) {
#pragma unroll
        for (int r = 0; r < 4; ++r) {
            const int px = mf * 16 + q * 4 + r;
            const int yl = px >> 5, xl = px & 31;
            const int opx = (2 * yl + qy) * 64 + 2 * xl + qx;
            float v0 = fmaxf(acc[mf][0][r] + bb0, 0.f);
            float v1 = fmaxf(acc[mf][1][r] + bb1, 0.f);
            bf16 b0 = f2b(v0), b1 = f2b(v1);
            s_mem[opx * 32 + m] = *(unsigned short*)&b0;
            s_mem[opx * 32 + 16 + m] = *(unsigned short*)&b1;
        }
    }
    __syncthreads();
    for (int g = tid; g < 2048; g += 256) {
        const int o = g * 8;
        *(uint4*)((unsigned short*)out + ((size_t)z * 3072 + bx * 512) * 32 + o) =
            *(const uint4*)&s_mem[o];
    }
}

// ---------------------------------------------------------------------------
// conv5: 3x3, 32->1, no ReLU. in NHWC bf16 (cnt,48,64,32) -> cost fp32
// ---------------------------------------------------------------------------
__global__ __launch_bounds__(256) void conv5_k(const bf16* __restrict__ in_,
                                               const float* __restrict__ w5,
                                               const float* __restrict__ b5,
                                               float* __restrict__ cost, int bd0, int cnt) {
    __shared__ float s_w5[9][32];
    const int tid = threadIdx.x;
    for (int i = tid; i < 288; i += 256) {
        int ic = i % 32, t = i / 32;
        s_w5[t][ic] = w5[ic * 9 + t];
    }
    __syncthreads();
    int idx = blockIdx.x * 256 + tid;
    if (idx >= cnt * 3072) return;
    int p = idx % 3072, z = idx / 3072;
    int y = p >> 6, x = p & 63;
    const unsigned short* in = (const unsigned short*)in_;
    float acc = b5[0];
#pragma unroll
    for (int ky = 0; ky < 3; ++ky) {
        int gy = y + ky - 1;
        if (gy < 0 || gy >= 48) continue;
#pragma unroll
        for (int kx = 0; kx < 3; ++kx) {
            int gx = x + kx - 1;
            if (gx < 0 || gx >= 64) continue;
            const ushort4* src = (const ushort4*)(in + ((size_t)(z * 48 + gy) * 64 + gx) * 32);
            const float* wr = s_w5[ky * 3 + kx];
#pragma unroll
            for (int e = 0; e < 8; ++e) {
                ushort4 u = src[e];
                acc = fmaf(us2f(u.x), wr[e * 4 + 0], acc);
                acc = fmaf(us2f(u.y), wr[e * 4 + 1], acc);
                acc = fmaf(us2f(u.z), wr[e * 4 + 2], acc);
                acc = fmaf(us2f(u.w), wr[e * 4 + 3], acc);
            }
        }
    }
    cost[(size_t)(bd0 + z) * 3072 + p] = acc;
}

// ---------------------------------------------------------------------------
// DAP (49x49) + softmax + flow expectation + coords. out fp32 (2,2,48,64)
// ---------------------------------------------------------------------------
__global__ __launch_bounds__(256) void dap_flow(const float* __restrict__ cost,
                                                const float* __restrict__ wdap,
                                                const float* __restrict__ coords,
                                                float* __restrict__ outp) {
    __shared__ float s_w[49 * 49];
    int tid = threadIdx.x;
    for (int i = tid; i < 2401; i += 256) s_w[i] = wdap[i];
    __syncthreads();
    int idx = blockIdx.x * 256 + tid;
    if (idx >= 2 * 3072) return;
    int p = idx % 3072, b = idx / 3072;
    float c[49];
#pragma unroll
    for (int d = 0; d < 49; ++d) c[d] = cost[((size_t)(b * 49 + d)) * 3072 + p];
    float mx = -1e30f;
    for (int e = 0; e < 49; ++e) {
        float s = 0.f;
#pragma unroll
        for (int d = 0; d < 49; ++d) s = fmaf(s_w[e * 49 + d], c[d], s);
        mx = fmaxf(mx, s);
    }
    float sum = 0.f, sx = 0.f, sy = 0.f;
    for (int e = 0; e < 49; ++e) {
        float s = 0.f;
#pragma unroll
        for (int d = 0; d < 49; ++d) s = fmaf(s_w[e * 49 + d], c[d], s);
        float pr = __expf(s - mx);
        sum += pr;
        sx += pr * (float)(e % 7 - 3);
        sy += pr * (float)(e / 7 - 3);
    }
    float inv = 1.f / sum;
    outp[(size_t)(b * 2 + 0) * 3072 + p] = coords[(size_t)(b * 2 + 0) * 3072 + p] + sx * inv;
    outp[(size_t)(b * 2 + 1) * 3072 + p] = coords[(size_t)(b * 2 + 1) * 3072 + p] + sy * inv;
}

// ---------------------------------------------------------------------------
extern "C" void kernel_launch(void* const* d_in, const int* in_sizes, int n_in,
                              void* d_out, int out_size, void* d_ws, size_t ws_size,
                              hipStream_t stream) {
    (void)in_sizes; (void)n_in;
    const float* feat1 = (const float*)d_in[0];
    const float* feat2 = (const float*)d_in[1];
    const float* coords = (const float*)d_in[2];
    const float* w0 = (const float*)d_in[3];
    const float* b0 = (const float*)d_in[4];
    const float* w1 = (const float*)d_in[5];
    const float* b1 = (const float*)d_in[6];
    const float* w2 = (const float*)d_in[7];
    const float* b2 = (const float*)d_in[8];
    const float* w3 = (const float*)d_in[9];
    const float* b3 = (const float*)d_in[10];
    const float* wd = (const float*)d_in[11];
    const float* bdc = (const float*)d_in[12];
    const float* w5 = (const float*)d_in[13];
    const float* b5 = (const float*)d_in[14];
    const float* wdap = (const float*)d_in[15];
    float* outp = (float*)d_out;

    // workspace (fixed):
    //  wsw0 @0 (110592) | wsw0a @110592 (110592) | wsw1 @221184 (393216)
    //  wsw2 @614400 (294912) | wsw3 @909312 (147456) | wswd @1056768 (65536)
    //  f1n @1122304 (786432) | part0(bf16) @1908736 (1179648) | cost @3088384 (1204224)
    //  f2n @4292608 (786432) | fixed_end = 5079040
    char* ws = (char*)d_ws;
    bf16* wsw0 = (bf16*)(ws + 0);
    bf16* wsw0a = (bf16*)(ws + 110592);
    bf16* wsw1 = (bf16*)(ws + 221184);
    bf16* wsw2 = (bf16*)(ws + 614400);
    bf16* wsw3 = (bf16*)(ws + 909312);
    bf16* wswd = (bf16*)(ws + 1056768);
    bf16* f1n = (bf16*)(ws + 1122304);
    bf16* part0 = (bf16*)(ws + 1908736);
    float* cost = (float*)(ws + 3088384);
    bf16* f2n = (bf16*)(ws + 4292608);
    const size_t fixed_end = 5079040;

    const int cand[7] = {98, 49, 25, 14, 7, 2, 1};
    int nb = 0;
    for (int i = 0; i < 7; ++i) {
        if (fixed_end + (size_t)983040 * cand[i] <= ws_size) { nb = cand[i]; break; }
    }
    if (nb == 0) {
        float val = 10000.f + (float)(ws_size >> 20);
        sentinel_k<<<dim3((out_size + 255) / 256), 256, 0, stream>>>(outp, out_size, val);
        return;
    }
    char* regA = ws + fixed_end;
    char* regB = regA + (size_t)393216 * nb;
    bf16* f2w = (bf16*)regA;  // (nb,48,64,64)
    bf16* x1 = (bf16*)regA;   // (nb,24,32,128)
    bf16* x3 = (bf16*)regA;   // (nb,24,32,64)
    bf16* x0p = (bf16*)regB;  // (nb,24,32,384) parity-packed
    bf16* x2 = (bf16*)regB;   // (nb,24,32,128)
    bf16* xd = (bf16*)regB;   // (nb,48,64,32)

    // prologue
    pack_all<<<dim3(2192), 256, 0, stream>>>(w0, w1, w2, w3, wd, wsw0, wsw0a, wsw1, wsw2, wsw3,
                                             wswd);
    to_nhwc2<<<dim3(3072), 256, 0, stream>>>(feat1, feat2, f1n, f2n);
    // part0 = conv3x3(f1n, w0[:,:64]) + b0 -> bf16 NHWC (2,48,64,96), no ReLU
    conv_px4<64, 96, 96, 48, 64, 2, 9, 3, -1, -1, 0, 4>
        <<<dim3(24, 1, 2), 256, 0, stream>>>(f1n, wsw0a, b0, nullptr, part0, 0);

    for (int s = 0; s < 98; s += nb) {
        int cnt = (98 - s < nb) ? (98 - s) : nb;
        warp_kernel<<<dim3(cnt * 96), 256, 0, stream>>>(f2n, coords, f2w, s, cnt);
        // conv0: IC=64 taps3x3 OC=96, base=part0(bf16), parity-pack out
        conv_px4<64, 96, 96, 48, 64, 2, 9, 3, -1, -1, 1, 1>
            <<<dim3(24, 1, cnt), 256, 0, stream>>>(f2w, wsw0, nullptr, part0, x0p, s);
        // conv1: IC=384 taps{-1,0}^2 OC=128, oc split 2
        conv_px4<384, 128, 64, 24, 32, 4, 4, 2, -1, -1, 0, 0>
            <<<dim3(6, 2, cnt), 256, 0, stream>>>(x0p, wsw1, b1, nullptr, x1, s);
        // conv2: IC=128 taps3x3 OC=128, oc split 2
        conv_px4<128, 128, 64, 24, 32, 4, 9, 3, -1, -1, 0, 0>
            <<<dim3(6, 2, cnt), 256, 0, stream>>>(x1, wsw2, b2, nullptr, x2, s);
        // conv3: IC=128 taps3x3 OC=64, no oc split (NfT=4)
        conv_px4<128, 64, 64, 24, 32, 4, 9, 3, -1, -1, 0, 0>
            <<<dim3(6, 1, cnt), 256, 0, stream>>>(x2, wsw3, b3, nullptr, x3, s);
        // deconv: merged 4 classes (wave=class)
        deconv_c4<<<dim3(6, cnt), 256, 0, stream>>>(x3, wswd, bdc, xd);
        // conv5
        conv5_k<<<dim3(cnt * 12), 256, 0, stream>>>(xd, w5, b5, cost, s, cnt);
    }

    dap_flow<<<dim3(24), 256, 0, stream>>>(cost, wdap, coords, outp);
}